// Round 2
// baseline (1138.502 us; speedup 1.0000x reference)
//
#include <hip/hip_runtime.h>

// RGAT: 2-layer, 2-relation GAT. N=20000 nodes, E=320000 edges/rel, D=128, H=2.
// Float tensor dtype is auto-detected at runtime (fp32 vs bf16) and normalized
// into internal bf16 copies. CSR built per relation once (shared by layers).
// Pipeline: convert -> CSR -> [GEMM -> el/er -> edge logits -> per-dst softmax
// -> fused dual-relation aggregate(+bias,+head-mean,+relu)] x 2 layers.

#define NN 20000
#define NE 320000

typedef unsigned short bf16_t;

__device__ __forceinline__ float bf2f(bf16_t u) {
    return __uint_as_float(((unsigned)u) << 16);
}
__device__ __forceinline__ bf16_t f2bf(float f) {
    unsigned x = __float_as_uint(f);
    unsigned r = (x + 0x7fffu + ((x >> 16) & 1u)) >> 16;   // RNE
    return (bf16_t)r;
}

// ---------------- dtype detection ----------------
// If x is fp32, the LOW 16 bits of each 32-bit word are random mantissa bits;
// as bf16 they are astronomically large with overwhelming probability.
// If x is bf16, every 16-bit half is a real data value (|v| < ~10).
__global__ void detect_kernel(const unsigned* __restrict__ x, int* __restrict__ flag) {
    float mx = 0.f;
    for (int i = 0; i < 256; ++i) {
        float v = fabsf(bf2f((bf16_t)(x[i] & 0xffffu)));
        if (v <= 1e30f) mx = fmaxf(mx, v);   // ignore NaN/inf encodings (already decisive)
        else mx = 1e30f;
    }
    *flag = (mx > 1e6f) ? 1 : 0;             // 1 = fp32 source data
}

// ---------------- batched conversion of all float tensors to internal bf16 ----
#define NT 17
struct ConvArgs {
    const void* src[NT];
    bf16_t* dst[NT];
    int n[NT];
};
__global__ void convert_kernel(ConvArgs a, const int* __restrict__ flag) {
    int ti = blockIdx.y;
    int n = a.n[ti];
    int i = blockIdx.x * 256 + threadIdx.x;
    if (i >= n) return;
    if (*flag) a.dst[ti][i] = f2bf(((const float*)a.src[ti])[i]);
    else       a.dst[ti][i] = ((const bf16_t*)a.src[ti])[i];
}

// ---------------- CSR build ----------------
__global__ void zero_i32(int* __restrict__ p, int n) {
    int i = blockIdx.x * 256 + threadIdx.x;
    if (i < n) p[i] = 0;
}

__global__ void hist_kernel(const int* __restrict__ dst, int* __restrict__ cnt, int e) {
    int i = blockIdx.x * 256 + threadIdx.x;
    if (i < e) atomicAdd(&cnt[dst[i]], 1);
}

// single block, 256 threads: exclusive scan of cnt[0..n) -> offs[0..n], cursor copy
__global__ void scan_kernel(const int* __restrict__ cnt, int* __restrict__ offs,
                            int* __restrict__ cursor, int n) {
    __shared__ int sums[256];
    int t = threadIdx.x;
    int chunk = (n + 255) >> 8;
    int lo = t * chunk;
    int hi = min(lo + chunk, n);
    int s = 0;
    for (int i = lo; i < hi; ++i) s += cnt[i];
    sums[t] = s;
    __syncthreads();
    if (t == 0) {
        int run = 0;
        for (int i = 0; i < 256; ++i) { int v = sums[i]; sums[i] = run; run += v; }
    }
    __syncthreads();
    int run = sums[t];
    for (int i = lo; i < hi; ++i) { int v = cnt[i]; offs[i] = run; cursor[i] = run; run += v; }
    if (t == 255) offs[n] = run;   // thread 255's range is empty for n=20000; run == E
}

__global__ void scatter_kernel(const int* __restrict__ dst, int* __restrict__ cursor,
                               int* __restrict__ perm, int e) {
    int i = blockIdx.x * 256 + threadIdx.x;
    if (i < e) {
        int p = atomicAdd(&cursor[dst[i]], 1);
        perm[p] = i;
    }
}

// ---------------- GEMM: C[n,M] = A[n,K] @ W[K,M], bf16 in, fp32 acc, bf16 out ----
// grid (M/256, n/8), block 256. 8 rows staged in LDS as fp32 (broadcast reads).
template <int K, int M>
__global__ void gemm_kernel(const bf16_t* __restrict__ A, const bf16_t* __restrict__ W,
                            bf16_t* __restrict__ C, int n) {
    __shared__ float As[8 * K];
    int t = threadIdx.x;
    int row0 = blockIdx.y * 8;
    for (int idx = t; idx < 8 * K; idx += 256) {
        int r = idx / K;
        int k = idx - r * K;
        int row = row0 + r;
        As[idx] = (row < n) ? bf2f(A[row * K + k]) : 0.0f;
    }
    __syncthreads();
    int col = blockIdx.x * 256 + t;
    float acc[8];
#pragma unroll
    for (int r = 0; r < 8; ++r) acc[r] = 0.f;
#pragma unroll 4
    for (int k = 0; k < K; ++k) {
        float w = bf2f(W[k * M + col]);
#pragma unroll
        for (int r = 0; r < 8; ++r) acc[r] += As[r * K + k] * w;
    }
#pragma unroll
    for (int r = 0; r < 8; ++r) {
        int row = row0 + r;
        if (row < n) C[row * M + col] = f2bf(acc[r]);
    }
}

// ---------------- el/er: one wave per (node, head) ----------------
template <int O>
__global__ void elr_kernel(const bf16_t* __restrict__ feat, const bf16_t* __restrict__ al,
                           const bf16_t* __restrict__ ar, float* __restrict__ el,
                           float* __restrict__ er, int n) {
    int w = blockIdx.x * 4 + (threadIdx.x >> 6);
    int lane = threadIdx.x & 63;
    if (w >= n * 2) return;
    int node = w >> 1;
    int h = w & 1;
    const bf16_t* f = feat + node * (2 * O) + h * O;
    const bf16_t* alh = al + h * O;
    const bf16_t* arh = ar + h * O;
    float sl = 0.f, sr = 0.f;
    for (int o = lane; o < O; o += 64) {
        float fv = bf2f(f[o]);
        sl += fv * bf2f(alh[o]);
        sr += fv * bf2f(arh[o]);
    }
    for (int off = 32; off > 0; off >>= 1) {
        sl += __shfl_xor(sl, off);
        sr += __shfl_xor(sr, off);
    }
    if (lane == 0) {
        el[node * 2 + h] = sl;
        er[node * 2 + h] = sr;
    }
}

// ---------------- per-edge logits e = leaky_relu(el[src]+er[dst], 0.2) ----------
__global__ void edge_e_kernel(const int* __restrict__ src, const int* __restrict__ dst,
                              const float* __restrict__ el, const float* __restrict__ er,
                              float* __restrict__ ebuf, int e) {
    int i = blockIdx.x * 256 + threadIdx.x;
    if (i >= e) return;
    int s = src[i];
    int d = dst[i];
#pragma unroll
    for (int h = 0; h < 2; ++h) {
        float v = el[s * 2 + h] + er[d * 2 + h];
        ebuf[i * 2 + h] = (v > 0.f) ? v : 0.2f * v;
    }
}

// ---------------- per-(dst,head) softmax over incoming edges, in-place e->alpha --
__global__ void softmax_kernel(const int* __restrict__ offs, const int* __restrict__ perm,
                               float* __restrict__ alpha, int n) {
    int idx = blockIdx.x * 256 + threadIdx.x;
    if (idx >= n * 2) return;
    int d = idx >> 1;
    int h = idx & 1;
    int beg = offs[d];
    int end = offs[d + 1];
    if (beg >= end) return;
    float m = -1e30f;
    for (int j = beg; j < end; ++j) m = fmaxf(m, alpha[perm[j] * 2 + h]);
    float ssum = 0.f;
    for (int j = beg; j < end; ++j) {
        float v = expf(alpha[perm[j] * 2 + h] - m);
        alpha[perm[j] * 2 + h] = v;
        ssum += v;
    }
    float inv = 1.0f / fmaxf(ssum, 1e-9f);
    for (int j = beg; j < end; ++j) alpha[perm[j] * 2 + h] *= inv;
}

// ---------------- fused aggregate: both relations + bias + head-mean (+relu) ----
// One block per dst node, blockDim = O (dims per head). Thread t owns packed
// bf16 pair (dims 2t, 2t+1) of the 2*O-wide feat row; head h = t/(O/2).
// Head-mean via LDS transpose-free exchange: sh[dim] then out[o]=.5*(sh[o]+sh[O+o]).
template <int O, bool FINAL>
__global__ void agg_fused_kernel(
    const int* __restrict__ offs0, const int* __restrict__ perm0,
    const int* __restrict__ src0, const float* __restrict__ alpha0,
    const bf16_t* __restrict__ feat0,
    const int* __restrict__ offs1, const int* __restrict__ perm1,
    const int* __restrict__ src1, const float* __restrict__ alpha1,
    const bf16_t* __restrict__ feat1,
    const bf16_t* __restrict__ b0, const bf16_t* __restrict__ b1,
    void* __restrict__ out, const int* __restrict__ flag) {
    __shared__ float sh[2 * O];
    int d = blockIdx.x;
    int t = threadIdx.x;               // [0, O)
    int h = t / (O / 2);
    float a0 = 0.f, a1 = 0.f;
    {
        int beg = offs0[d], end = offs0[d + 1];
        const unsigned* f = (const unsigned*)feat0;   // row = O unsigneds
        for (int j = beg; j < end; ++j) {
            int ei = perm0[j];
            int s = src0[ei];
            float al = alpha0[ei * 2 + h];
            unsigned pk = f[s * O + t];
            a0 += al * bf2f((bf16_t)(pk & 0xffffu));
            a1 += al * bf2f((bf16_t)(pk >> 16));
        }
    }
    {
        int beg = offs1[d], end = offs1[d + 1];
        const unsigned* f = (const unsigned*)feat1;
        for (int j = beg; j < end; ++j) {
            int ei = perm1[j];
            int s = src1[ei];
            float al = alpha1[ei * 2 + h];
            unsigned pk = f[s * O + t];
            a0 += al * bf2f((bf16_t)(pk & 0xffffu));
            a1 += al * bf2f((bf16_t)(pk >> 16));
        }
    }
    sh[2 * t] = a0;
    sh[2 * t + 1] = a1;
    __syncthreads();
    int o = t;
    float v = sh[o] + sh[O + o]
            + bf2f(b0[o]) + bf2f(b0[O + o]) + bf2f(b1[o]) + bf2f(b1[O + o]);
    v *= 0.5f;
    if (!FINAL) {
        ((bf16_t*)out)[d * O + o] = f2bf(fmaxf(v, 0.f));
    } else {
        if (*flag) ((float*)out)[d * O + o] = v;
        else       ((bf16_t*)out)[d * O + o] = f2bf(v);
    }
}

extern "C" void kernel_launch(void* const* d_in, const int* in_sizes, int n_in,
                              void* d_out, int out_size, void* d_ws, size_t ws_size,
                              hipStream_t stream) {
    const int* src0 = (const int*)d_in[1];
    const int* dst0 = (const int*)d_in[2];
    const int* src1 = (const int*)d_in[3];
    const int* dst1 = (const int*)d_in[4];

    char* ws = (char*)d_ws;
    size_t off = 0;
    auto alloc = [&](size_t bytes) -> void* {
        void* p = ws + off;
        off = (off + bytes + 255) & ~(size_t)255;
        return p;
    };
    int* flag = (int*)alloc(4);
    // internal bf16 copies of all float tensors
    static const int tn[NT] = {NN * 128,                 // x
                               128 * 512, 512, 512, 512, // W1_0, al1_0, ar1_0, b1_0
                               128 * 512, 512, 512, 512, // W1_1 ...
                               256 * 256, 256, 256, 256, // W2_0 ...
                               256 * 256, 256, 256, 256};// W2_1 ...
    bf16_t* tb[NT];
    for (int i = 0; i < NT; ++i) tb[i] = (bf16_t*)alloc((size_t)tn[i] * 2);
    bf16_t* xb    = tb[0];
    bf16_t* W1_0b = tb[1],  *al1_0b = tb[2],  *ar1_0b = tb[3],  *b1_0b = tb[4];
    bf16_t* W1_1b = tb[5],  *al1_1b = tb[6],  *ar1_1b = tb[7],  *b1_1b = tb[8];
    bf16_t* W2_0b = tb[9],  *al2_0b = tb[10], *ar2_0b = tb[11], *b2_0b = tb[12];
    bf16_t* W2_1b = tb[13], *al2_1b = tb[14], *ar2_1b = tb[15], *b2_1b = tb[16];

    int*    cnt0  = (int*)alloc(NN * 4);
    int*    cnt1  = (int*)alloc(NN * 4);
    int*    offs0 = (int*)alloc((NN + 1) * 4);
    int*    offs1 = (int*)alloc((NN + 1) * 4);
    int*    cur0  = (int*)alloc(NN * 4);
    int*    cur1  = (int*)alloc(NN * 4);
    int*    perm0 = (int*)alloc(NE * 4);
    int*    perm1 = (int*)alloc(NE * 4);
    float*  el0   = (float*)alloc(NN * 2 * 4);
    float*  er0   = (float*)alloc(NN * 2 * 4);
    float*  el1   = (float*)alloc(NN * 2 * 4);
    float*  er1   = (float*)alloc(NN * 2 * 4);
    float*  e0    = (float*)alloc((size_t)NE * 2 * 4);
    float*  e1    = (float*)alloc((size_t)NE * 2 * 4);
    bf16_t* featA = (bf16_t*)alloc((size_t)NN * 512 * 2);
    bf16_t* featB = (bf16_t*)alloc((size_t)NN * 512 * 2);
    bf16_t* h1    = (bf16_t*)alloc((size_t)NN * 256 * 2);
    (void)ws_size;  // total ~66 MB

    // dtype detect + normalize
    detect_kernel<<<1, 1, 0, stream>>>((const unsigned*)d_in[0], flag);
    ConvArgs ca;
    // d_in indices of the 17 float tensors, in tb[] order
    static const int din_idx[NT] = {0, 5, 6, 7, 8, 9, 10, 11, 12,
                                    13, 14, 15, 16, 17, 18, 19, 20};
    int maxn = 0;
    for (int i = 0; i < NT; ++i) {
        ca.src[i] = d_in[din_idx[i]];
        ca.dst[i] = tb[i];
        ca.n[i] = tn[i];
        if (tn[i] > maxn) maxn = tn[i];
    }
    convert_kernel<<<dim3((maxn + 255) / 256, NT), 256, 0, stream>>>(ca, flag);

    const int EB = (NE + 255) / 256;       // 1250
    const int NB = (NN + 255) / 256;       // 79
    const int NHB = (NN * 2 + 255) / 256;  // 157

    // CSR build (shared by both layers)
    zero_i32<<<NB, 256, 0, stream>>>(cnt0, NN);
    zero_i32<<<NB, 256, 0, stream>>>(cnt1, NN);
    hist_kernel<<<EB, 256, 0, stream>>>(dst0, cnt0, NE);
    hist_kernel<<<EB, 256, 0, stream>>>(dst1, cnt1, NE);
    scan_kernel<<<1, 256, 0, stream>>>(cnt0, offs0, cur0, NN);
    scan_kernel<<<1, 256, 0, stream>>>(cnt1, offs1, cur1, NN);
    scatter_kernel<<<EB, 256, 0, stream>>>(dst0, cur0, perm0, NE);
    scatter_kernel<<<EB, 256, 0, stream>>>(dst1, cur1, perm1, NE);

    // ---- Layer 1: in=128, O=256/head, M=512 ----
    gemm_kernel<128, 512><<<dim3(2, NN / 8), 256, 0, stream>>>(xb, W1_0b, featA, NN);
    gemm_kernel<128, 512><<<dim3(2, NN / 8), 256, 0, stream>>>(xb, W1_1b, featB, NN);
    elr_kernel<256><<<10000, 256, 0, stream>>>(featA, al1_0b, ar1_0b, el0, er0, NN);
    elr_kernel<256><<<10000, 256, 0, stream>>>(featB, al1_1b, ar1_1b, el1, er1, NN);
    edge_e_kernel<<<EB, 256, 0, stream>>>(src0, dst0, el0, er0, e0, NE);
    edge_e_kernel<<<EB, 256, 0, stream>>>(src1, dst1, el1, er1, e1, NE);
    softmax_kernel<<<NHB, 256, 0, stream>>>(offs0, perm0, e0, NN);
    softmax_kernel<<<NHB, 256, 0, stream>>>(offs1, perm1, e1, NN);
    agg_fused_kernel<256, false><<<NN, 256, 0, stream>>>(
        offs0, perm0, src0, e0, featA, offs1, perm1, src1, e1, featB,
        b1_0b, b1_1b, h1, flag);

    // ---- Layer 2: in=256, O=128/head, M=256 ----
    gemm_kernel<256, 256><<<dim3(1, NN / 8), 256, 0, stream>>>(h1, W2_0b, featA, NN);
    gemm_kernel<256, 256><<<dim3(1, NN / 8), 256, 0, stream>>>(h1, W2_1b, featB, NN);
    elr_kernel<128><<<10000, 256, 0, stream>>>(featA, al2_0b, ar2_0b, el0, er0, NN);
    elr_kernel<128><<<10000, 256, 0, stream>>>(featB, al2_1b, ar2_1b, el1, er1, NN);
    edge_e_kernel<<<EB, 256, 0, stream>>>(src0, dst0, el0, er0, e0, NE);
    edge_e_kernel<<<EB, 256, 0, stream>>>(src1, dst1, el1, er1, e1, NE);
    softmax_kernel<<<NHB, 256, 0, stream>>>(offs0, perm0, e0, NN);
    softmax_kernel<<<NHB, 256, 0, stream>>>(offs1, perm1, e1, NN);
    agg_fused_kernel<128, true><<<NN, 128, 0, stream>>>(
        offs0, perm0, src0, e0, featA, offs1, perm1, src1, e1, featB,
        b2_0b, b2_1b, d_out, flag);
}

// Round 3
// 707.038 us; speedup vs baseline: 1.6102x; 1.6102x over previous
//
#include <hip/hip_runtime.h>

// RGAT: 2-layer, 2-relation GAT. N=20000, E=320000/rel, D=128, H=2.
// Round 3: (1) agg: 4 waves/block each gathering full rows (4x MLP),
// (2) MFMA GEMMs with weight repack to B-fragment order,
// (3) CSR-ordered alpha + src_csr (edge_e kernel and perm indirection removed).

#define NN 20000
#define NE 320000

typedef unsigned short bf16_t;
typedef __attribute__((ext_vector_type(8))) short short8;
typedef __attribute__((ext_vector_type(4))) float f32x4;

__device__ __forceinline__ float bf2f(bf16_t u) {
    return __uint_as_float(((unsigned)u) << 16);
}
__device__ __forceinline__ bf16_t f2bf(float f) {
    unsigned x = __float_as_uint(f);
    unsigned r = (x + 0x7fffu + ((x >> 16) & 1u)) >> 16;   // RNE
    return (bf16_t)r;
}

// ---------------- dtype detection (fp32 vs bf16 source) ----------------
__global__ void detect_kernel(const unsigned* __restrict__ x, int* __restrict__ flag) {
    float mx = 0.f;
    for (int i = 0; i < 256; ++i) {
        float v = fabsf(bf2f((bf16_t)(x[i] & 0xffffu)));
        if (v <= 1e30f) mx = fmaxf(mx, v);
        else mx = 1e30f;
    }
    *flag = (mx > 1e6f) ? 1 : 0;   // 1 = fp32 source
}

// ---------------- batched conversion of all float tensors to bf16 ----
#define NT 17
struct ConvArgs {
    const void* src[NT];
    bf16_t* dst[NT];
    int n[NT];
};
__global__ void convert_kernel(ConvArgs a, const int* __restrict__ flag) {
    int ti = blockIdx.y;
    int n = a.n[ti];
    int i = blockIdx.x * 256 + threadIdx.x;
    if (i >= n) return;
    if (*flag) a.dst[ti][i] = f2bf(((const float*)a.src[ti])[i]);
    else       a.dst[ti][i] = ((const bf16_t*)a.src[ti])[i];
}

// ---------------- weight repack: row-major W[K,M] -> MFMA B-frag order ------
// Wf[((ct*KS + ks)*64 + lane)*8 + j] = W[(ks*32 + (lane>>4)*8 + j)*M + ct*16 + (lane&15)]
// All 4 weights have K*M = 65536 -> 8192 threads each.
struct RepackArgs {
    const bf16_t* src[4];
    bf16_t* dst[4];
    int K[4];
    int M[4];
};
__global__ void repack_kernel(RepackArgs ra) {
    int wi = blockIdx.y;
    const bf16_t* W = ra.src[wi];
    bf16_t* Wf = ra.dst[wi];
    int K = ra.K[wi], M = ra.M[wi];
    int i = blockIdx.x * 256 + threadIdx.x;          // (ct*KS+ks)*64 + lane
    int total = (M >> 4) * (K >> 5) * 64;
    if (i >= total) return;
    int lane = i & 63;
    int t = i >> 6;
    int KS = K >> 5;
    int ct = t / KS, ks = t - ct * KS;
    int kbase = ks * 32 + (lane >> 4) * 8;
    int col = ct * 16 + (lane & 15);
    bf16_t* out = Wf + (size_t)i * 8;
#pragma unroll
    for (int j = 0; j < 8; ++j) out[j] = W[(size_t)(kbase + j) * M + col];
}

// ---------------- CSR build ----------------
__global__ void zero_i32(int* __restrict__ p, int n) {
    int i = blockIdx.x * 256 + threadIdx.x;
    if (i < n) p[i] = 0;
}

__global__ void hist_kernel(const int* __restrict__ dst, int* __restrict__ cnt, int e) {
    int i = blockIdx.x * 256 + threadIdx.x;
    if (i < e) atomicAdd(&cnt[dst[i]], 1);
}

__global__ void scan_kernel(const int* __restrict__ cnt, int* __restrict__ offs,
                            int* __restrict__ cursor, int n) {
    __shared__ int sums[256];
    int t = threadIdx.x;
    int chunk = (n + 255) >> 8;
    int lo = t * chunk;
    int hi = min(lo + chunk, n);
    int s = 0;
    for (int i = lo; i < hi; ++i) s += cnt[i];
    sums[t] = s;
    __syncthreads();
    if (t == 0) {
        int run = 0;
        for (int i = 0; i < 256; ++i) { int v = sums[i]; sums[i] = run; run += v; }
    }
    __syncthreads();
    int run = sums[t];
    for (int i = lo; i < hi; ++i) { int v = cnt[i]; offs[i] = run; cursor[i] = run; run += v; }
    if (t == 255) offs[n] = run;
}

// scatter writes src_csr directly (perm is never needed downstream)
__global__ void scatter_kernel(const int* __restrict__ src, const int* __restrict__ dst,
                               int* __restrict__ cursor, int* __restrict__ src_csr, int e) {
    int i = blockIdx.x * 256 + threadIdx.x;
    if (i < e) {
        int p = atomicAdd(&cursor[dst[i]], 1);
        src_csr[p] = src[i];
    }
}

// ---------------- MFMA GEMM: C[n,M] = A[n,K] @ W[K,M] ----------------
// block 256 = 4 waves; wave computes 16 rows x 64 cols; grid (M/64, ceil(n/64)).
// A loaded directly (16B/lane frags); W pre-repacked to frag order (Wf).
template <int K, int M>
__global__ void gemm_mfma(const bf16_t* __restrict__ A, const bf16_t* __restrict__ Wf,
                          bf16_t* __restrict__ C, int n) {
    int w = threadIdx.x >> 6, lane = threadIdx.x & 63;
    int q = lane >> 4, m16 = lane & 15;
    int rf = blockIdx.y * 64 + w * 16;
    if (rf >= n) return;               // n % 16 == 0: frag fully in or out; no barriers used
    constexpr int KS = K / 32;
    f32x4 acc[4] = {};
    const bf16_t* Arow = A + (size_t)(rf + m16) * K + q * 8;
    for (int ks = 0; ks < KS; ++ks) {
        short8 af = *(const short8*)(Arow + ks * 32);
#pragma unroll
        for (int f = 0; f < 4; ++f) {
            int ct = blockIdx.x * 4 + f;
            short8 bfr = *(const short8*)(Wf + ((size_t)(ct * KS + ks) * 64 + lane) * 8);
            acc[f] = __builtin_amdgcn_mfma_f32_16x16x32_bf16(af, bfr, acc[f], 0, 0, 0);
        }
    }
    int col0 = blockIdx.x * 64;
#pragma unroll
    for (int f = 0; f < 4; ++f) {
#pragma unroll
        for (int r = 0; r < 4; ++r) {
            int row = rf + q * 4 + r;
            C[(size_t)row * M + col0 + f * 16 + m16] = f2bf(acc[f][r]);
        }
    }
}

// ---------------- el/er: one wave per (node, head) ----------------
template <int O>
__global__ void elr_kernel(const bf16_t* __restrict__ feat, const bf16_t* __restrict__ al,
                           const bf16_t* __restrict__ ar, float* __restrict__ el,
                           float* __restrict__ er, int n) {
    int w = blockIdx.x * 4 + (threadIdx.x >> 6);
    int lane = threadIdx.x & 63;
    if (w >= n * 2) return;
    int node = w >> 1;
    int h = w & 1;
    const bf16_t* f = feat + (size_t)node * (2 * O) + h * O;
    const bf16_t* alh = al + h * O;
    const bf16_t* arh = ar + h * O;
    float sl = 0.f, sr = 0.f;
    for (int o = lane; o < O; o += 64) {
        float fv = bf2f(f[o]);
        sl += fv * bf2f(alh[o]);
        sr += fv * bf2f(arh[o]);
    }
    for (int off = 32; off > 0; off >>= 1) {
        sl += __shfl_xor(sl, off);
        sr += __shfl_xor(sr, off);
    }
    if (lane == 0) {
        el[node * 2 + h] = sl;
        er[node * 2 + h] = sr;
    }
}

// ------- fused edge softmax, CSR order: alpha[2j+h] for edge slot j --------
__global__ void softmax_csr(const int* __restrict__ offs, const int* __restrict__ srcc,
                            const float* __restrict__ el, const float* __restrict__ er,
                            float* __restrict__ alpha, int n) {
    int d = blockIdx.x * 256 + threadIdx.x;
    if (d >= n) return;
    int beg = offs[d], end = offs[d + 1];
    if (beg >= end) return;
    float er0 = er[d * 2], er1 = er[d * 2 + 1];
    float m0 = -1e30f, m1 = -1e30f;
    for (int j = beg; j < end; ++j) {
        int s = srcc[j];
        float2 ev = ((const float2*)el)[s];
        float e0 = ev.x + er0;
        float e1 = ev.y + er1;
        e0 = (e0 > 0.f) ? e0 : 0.2f * e0;
        e1 = (e1 > 0.f) ? e1 : 0.2f * e1;
        alpha[2 * j] = e0;
        alpha[2 * j + 1] = e1;
        m0 = fmaxf(m0, e0);
        m1 = fmaxf(m1, e1);
    }
    float s0 = 0.f, s1 = 0.f;
    for (int j = beg; j < end; ++j) {
        float v0 = __expf(alpha[2 * j] - m0);
        float v1 = __expf(alpha[2 * j + 1] - m1);
        alpha[2 * j] = v0;
        alpha[2 * j + 1] = v1;
        s0 += v0;
        s1 += v1;
    }
    float i0 = 1.f / fmaxf(s0, 1e-9f);
    float i1 = 1.f / fmaxf(s1, 1e-9f);
    for (int j = beg; j < end; ++j) {
        alpha[2 * j] *= i0;
        alpha[2 * j + 1] *= i1;
    }
}

// ---------------- fused aggregate: 4 waves/block, each gathers full rows -----
// One dst per block. Wave w handles edges j = beg+w, step 4, loads the whole
// 2*O-dim row (VD dwords/lane), accumulates; partials merged in LDS, then
// bias + head-mean (+relu / final store).
template <int O, bool FINAL>
__global__ void agg_fused2(
    const int* __restrict__ offs0, const int* __restrict__ srcc0,
    const float* __restrict__ alpha0, const bf16_t* __restrict__ feat0,
    const int* __restrict__ offs1, const int* __restrict__ srcc1,
    const float* __restrict__ alpha1, const bf16_t* __restrict__ feat1,
    const bf16_t* __restrict__ b0, const bf16_t* __restrict__ b1,
    void* __restrict__ out, const int* __restrict__ flag) {
    constexpr int VD = (2 * O) / 128;     // dwords per lane: 4 (O=256) / 2 (O=128)
    __shared__ float sh[4][2 * O];
    int d = blockIdx.x;
    int w = threadIdx.x >> 6, lane = threadIdx.x & 63;
    int head = lane >> 5;                 // lanes 0-31 = head 0 dims, 32-63 = head 1
    float acc[2 * VD];
#pragma unroll
    for (int k = 0; k < 2 * VD; ++k) acc[k] = 0.f;

    {
        int beg = offs0[d], end = offs0[d + 1];
        const unsigned* fp = (const unsigned*)feat0;
        for (int j = beg + w; j < end; j += 4) {
            int s = srcc0[j];
            float a = alpha0[2 * j + head];
            const unsigned* p = fp + (size_t)s * O + lane * VD;
            if constexpr (VD == 4) {
                uint4 pk = *(const uint4*)p;
                acc[0] += a * bf2f((bf16_t)(pk.x & 0xffffu));
                acc[1] += a * bf2f((bf16_t)(pk.x >> 16));
                acc[2] += a * bf2f((bf16_t)(pk.y & 0xffffu));
                acc[3] += a * bf2f((bf16_t)(pk.y >> 16));
                acc[4] += a * bf2f((bf16_t)(pk.z & 0xffffu));
                acc[5] += a * bf2f((bf16_t)(pk.z >> 16));
                acc[6] += a * bf2f((bf16_t)(pk.w & 0xffffu));
                acc[7] += a * bf2f((bf16_t)(pk.w >> 16));
            } else {
                uint2 pk = *(const uint2*)p;
                acc[0] += a * bf2f((bf16_t)(pk.x & 0xffffu));
                acc[1] += a * bf2f((bf16_t)(pk.x >> 16));
                acc[2] += a * bf2f((bf16_t)(pk.y & 0xffffu));
                acc[3] += a * bf2f((bf16_t)(pk.y >> 16));
            }
        }
    }
    {
        int beg = offs1[d], end = offs1[d + 1];
        const unsigned* fp = (const unsigned*)feat1;
        for (int j = beg + w; j < end; j += 4) {
            int s = srcc1[j];
            float a = alpha1[2 * j + head];
            const unsigned* p = fp + (size_t)s * O + lane * VD;
            if constexpr (VD == 4) {
                uint4 pk = *(const uint4*)p;
                acc[0] += a * bf2f((bf16_t)(pk.x & 0xffffu));
                acc[1] += a * bf2f((bf16_t)(pk.x >> 16));
                acc[2] += a * bf2f((bf16_t)(pk.y & 0xffffu));
                acc[3] += a * bf2f((bf16_t)(pk.y >> 16));
                acc[4] += a * bf2f((bf16_t)(pk.z & 0xffffu));
                acc[5] += a * bf2f((bf16_t)(pk.z >> 16));
                acc[6] += a * bf2f((bf16_t)(pk.w & 0xffffu));
                acc[7] += a * bf2f((bf16_t)(pk.w >> 16));
            } else {
                uint2 pk = *(const uint2*)p;
                acc[0] += a * bf2f((bf16_t)(pk.x & 0xffffu));
                acc[1] += a * bf2f((bf16_t)(pk.x >> 16));
                acc[2] += a * bf2f((bf16_t)(pk.y & 0xffffu));
                acc[3] += a * bf2f((bf16_t)(pk.y >> 16));
            }
        }
    }
#pragma unroll
    for (int k = 0; k < 2 * VD; ++k) sh[w][lane * (2 * VD) + k] = acc[k];
    __syncthreads();
    int o = threadIdx.x;
    if (o < O) {
        float v = 0.f;
#pragma unroll
        for (int ww = 0; ww < 4; ++ww) v += sh[ww][o] + sh[ww][o + O];
        v += bf2f(b0[o]) + bf2f(b0[O + o]) + bf2f(b1[o]) + bf2f(b1[O + o]);
        v *= 0.5f;
        if (!FINAL) {
            ((bf16_t*)out)[(size_t)d * O + o] = f2bf(fmaxf(v, 0.f));
        } else {
            if (*flag) ((float*)out)[(size_t)d * O + o] = v;
            else       ((bf16_t*)out)[(size_t)d * O + o] = f2bf(v);
        }
    }
}

extern "C" void kernel_launch(void* const* d_in, const int* in_sizes, int n_in,
                              void* d_out, int out_size, void* d_ws, size_t ws_size,
                              hipStream_t stream) {
    (void)in_sizes; (void)n_in; (void)out_size; (void)ws_size;
    const int* src0 = (const int*)d_in[1];
    const int* dst0 = (const int*)d_in[2];
    const int* src1 = (const int*)d_in[3];
    const int* dst1 = (const int*)d_in[4];

    char* ws = (char*)d_ws;
    size_t off = 0;
    auto alloc = [&](size_t bytes) -> void* {
        void* p = ws + off;
        off = (off + bytes + 255) & ~(size_t)255;
        return p;
    };
    int* flag = (int*)alloc(4);
    static const int tn[NT] = {NN * 128,
                               128 * 512, 512, 512, 512,
                               128 * 512, 512, 512, 512,
                               256 * 256, 256, 256, 256,
                               256 * 256, 256, 256, 256};
    bf16_t* tb[NT];
    for (int i = 0; i < NT; ++i) tb[i] = (bf16_t*)alloc((size_t)tn[i] * 2);
    bf16_t* xb    = tb[0];
    bf16_t* al1_0b = tb[2],  *ar1_0b = tb[3],  *b1_0b = tb[4];
    bf16_t* al1_1b = tb[6],  *ar1_1b = tb[7],  *b1_1b = tb[8];
    bf16_t* al2_0b = tb[10], *ar2_0b = tb[11], *b2_0b = tb[12];
    bf16_t* al2_1b = tb[14], *ar2_1b = tb[15], *b2_1b = tb[16];

    bf16_t* Wf[4];
    for (int i = 0; i < 4; ++i) Wf[i] = (bf16_t*)alloc((size_t)65536 * 2);

    int*    cnt0  = (int*)alloc(NN * 4);
    int*    cnt1  = (int*)alloc(NN * 4);
    int*    offs0 = (int*)alloc((NN + 1) * 4);
    int*    offs1 = (int*)alloc((NN + 1) * 4);
    int*    cur0  = (int*)alloc(NN * 4);
    int*    cur1  = (int*)alloc(NN * 4);
    int*    srcc0 = (int*)alloc(NE * 4);
    int*    srcc1 = (int*)alloc(NE * 4);
    float*  el0   = (float*)alloc(NN * 2 * 4);
    float*  er0   = (float*)alloc(NN * 2 * 4);
    float*  el1   = (float*)alloc(NN * 2 * 4);
    float*  er1   = (float*)alloc(NN * 2 * 4);
    float*  alp0  = (float*)alloc((size_t)NE * 2 * 4);
    float*  alp1  = (float*)alloc((size_t)NE * 2 * 4);
    bf16_t* featA = (bf16_t*)alloc((size_t)NN * 512 * 2);
    bf16_t* featB = (bf16_t*)alloc((size_t)NN * 512 * 2);
    bf16_t* h1    = (bf16_t*)alloc((size_t)NN * 256 * 2);

    // dtype detect + normalize
    detect_kernel<<<1, 1, 0, stream>>>((const unsigned*)d_in[0], flag);
    ConvArgs ca;
    static const int din_idx[NT] = {0, 5, 6, 7, 8, 9, 10, 11, 12,
                                    13, 14, 15, 16, 17, 18, 19, 20};
    int maxn = 0;
    for (int i = 0; i < NT; ++i) {
        ca.src[i] = d_in[din_idx[i]];
        ca.dst[i] = tb[i];
        ca.n[i] = tn[i];
        if (tn[i] > maxn) maxn = tn[i];
    }
    convert_kernel<<<dim3((maxn + 255) / 256, NT), 256, 0, stream>>>(ca, flag);

    // weight repack to MFMA B-frag order (after convert)
    RepackArgs ra;
    ra.src[0] = tb[1];  ra.K[0] = 128; ra.M[0] = 512;   // W1_0
    ra.src[1] = tb[5];  ra.K[1] = 128; ra.M[1] = 512;   // W1_1
    ra.src[2] = tb[9];  ra.K[2] = 256; ra.M[2] = 256;   // W2_0
    ra.src[3] = tb[13]; ra.K[3] = 256; ra.M[3] = 256;   // W2_1
    for (int i = 0; i < 4; ++i) ra.dst[i] = Wf[i];
    repack_kernel<<<dim3(32, 4), 256, 0, stream>>>(ra);

    const int EB = (NE + 255) / 256;
    const int NB = (NN + 255) / 256;

    // CSR build (shared by both layers)
    zero_i32<<<NB, 256, 0, stream>>>(cnt0, NN);
    zero_i32<<<NB, 256, 0, stream>>>(cnt1, NN);
    hist_kernel<<<EB, 256, 0, stream>>>(dst0, cnt0, NE);
    hist_kernel<<<EB, 256, 0, stream>>>(dst1, cnt1, NE);
    scan_kernel<<<1, 256, 0, stream>>>(cnt0, offs0, cur0, NN);
    scan_kernel<<<1, 256, 0, stream>>>(cnt1, offs1, cur1, NN);
    scatter_kernel<<<EB, 256, 0, stream>>>(src0, dst0, cur0, srcc0, NE);
    scatter_kernel<<<EB, 256, 0, stream>>>(src1, dst1, cur1, srcc1, NE);

    // ---- Layer 1: K=128, M=512, O=256/head ----
    gemm_mfma<128, 512><<<dim3(8, 313), 256, 0, stream>>>(xb, Wf[0], featA, NN);
    gemm_mfma<128, 512><<<dim3(8, 313), 256, 0, stream>>>(xb, Wf[1], featB, NN);
    elr_kernel<256><<<10000, 256, 0, stream>>>(featA, al1_0b, ar1_0b, el0, er0, NN);
    elr_kernel<256><<<10000, 256, 0, stream>>>(featB, al1_1b, ar1_1b, el1, er1, NN);
    softmax_csr<<<NB, 256, 0, stream>>>(offs0, srcc0, el0, er0, alp0, NN);
    softmax_csr<<<NB, 256, 0, stream>>>(offs1, srcc1, el1, er1, alp1, NN);
    agg_fused2<256, false><<<NN, 256, 0, stream>>>(
        offs0, srcc0, alp0, featA, offs1, srcc1, alp1, featB,
        b1_0b, b1_1b, h1, flag);

    // ---- Layer 2: K=256, M=256, O=128/head ----
    gemm_mfma<256, 256><<<dim3(4, 313), 256, 0, stream>>>(h1, Wf[2], featA, NN);
    gemm_mfma<256, 256><<<dim3(4, 313), 256, 0, stream>>>(h1, Wf[3], featB, NN);
    elr_kernel<128><<<10000, 256, 0, stream>>>(featA, al2_0b, ar2_0b, el0, er0, NN);
    elr_kernel<128><<<10000, 256, 0, stream>>>(featB, al2_1b, ar2_1b, el1, er1, NN);
    softmax_csr<<<NB, 256, 0, stream>>>(offs0, srcc0, el0, er0, alp0, NN);
    softmax_csr<<<NB, 256, 0, stream>>>(offs1, srcc1, el1, er1, alp1, NN);
    agg_fused2<128, true><<<NN, 256, 0, stream>>>(
        offs0, srcc0, alp0, featA, offs1, srcc1, alp1, featB,
        b2_0b, b2_1b, d_out, flag);
}

// Round 4
// 611.563 us; speedup vs baseline: 1.8616x; 1.1561x over previous
//
#include <hip/hip_runtime.h>

// RGAT: 2-layer, 2-relation GAT. N=20000, E=320000/rel, D=128, H=2.
// Round 4: (1) el/er fused into MFMA GEMM epilogue (atomicAdd partials),
// (2) edge softmax fused into agg (online-softmax phase + inline alpha in
// gather phase) -- elr_kernel and softmax_csr kernels removed entirely.

#define NN 20000
#define NE 320000

typedef unsigned short bf16_t;
typedef __attribute__((ext_vector_type(8))) short short8;
typedef __attribute__((ext_vector_type(4))) float f32x4;

__device__ __forceinline__ float bf2f(bf16_t u) {
    return __uint_as_float(((unsigned)u) << 16);
}
__device__ __forceinline__ bf16_t f2bf(float f) {
    unsigned x = __float_as_uint(f);
    unsigned r = (x + 0x7fffu + ((x >> 16) & 1u)) >> 16;   // RNE
    return (bf16_t)r;
}
__device__ __forceinline__ float lrelu(float v) {
    return (v > 0.f) ? v : 0.2f * v;
}

// ---------------- dtype detection (fp32 vs bf16 source) ----------------
__global__ void detect_kernel(const unsigned* __restrict__ x, int* __restrict__ flag) {
    float mx = 0.f;
    for (int i = 0; i < 256; ++i) {
        float v = fabsf(bf2f((bf16_t)(x[i] & 0xffffu)));
        if (v <= 1e30f) mx = fmaxf(mx, v);
        else mx = 1e30f;
    }
    *flag = (mx > 1e6f) ? 1 : 0;   // 1 = fp32 source
}

// ---------------- batched conversion of all float tensors to bf16 ----
#define NT 17
struct ConvArgs {
    const void* src[NT];
    bf16_t* dst[NT];
    int n[NT];
};
__global__ void convert_kernel(ConvArgs a, const int* __restrict__ flag) {
    int ti = blockIdx.y;
    int n = a.n[ti];
    int i = blockIdx.x * 256 + threadIdx.x;
    if (i >= n) return;
    if (*flag) a.dst[ti][i] = f2bf(((const float*)a.src[ti])[i]);
    else       a.dst[ti][i] = ((const bf16_t*)a.src[ti])[i];
}

// ---------------- weight repack: row-major W[K,M] -> MFMA B-frag order ------
struct RepackArgs {
    const bf16_t* src[4];
    bf16_t* dst[4];
    int K[4];
    int M[4];
};
__global__ void repack_kernel(RepackArgs ra) {
    int wi = blockIdx.y;
    const bf16_t* W = ra.src[wi];
    bf16_t* Wf = ra.dst[wi];
    int K = ra.K[wi], M = ra.M[wi];
    int i = blockIdx.x * 256 + threadIdx.x;          // (ct*KS+ks)*64 + lane
    int total = (M >> 4) * (K >> 5) * 64;
    if (i >= total) return;
    int lane = i & 63;
    int t = i >> 6;
    int KS = K >> 5;
    int ct = t / KS, ks = t - ct * KS;
    int kbase = ks * 32 + (lane >> 4) * 8;
    int col = ct * 16 + (lane & 15);
    bf16_t* out = Wf + (size_t)i * 8;
#pragma unroll
    for (int j = 0; j < 8; ++j) out[j] = W[(size_t)(kbase + j) * M + col];
}

// ---------------- CSR build ----------------
__global__ void zero_i32(int* __restrict__ p, int n) {
    int i = blockIdx.x * 256 + threadIdx.x;
    if (i < n) p[i] = 0;
}

// zero the 4 el/er buffers (contiguity not assumed)
__global__ void zero_elr(float* __restrict__ a, float* __restrict__ b,
                         float* __restrict__ c, float* __restrict__ d, int n) {
    int i = blockIdx.x * 256 + threadIdx.x;
    if (i < n) { a[i] = 0.f; b[i] = 0.f; c[i] = 0.f; d[i] = 0.f; }
}

__global__ void hist_kernel(const int* __restrict__ dst, int* __restrict__ cnt, int e) {
    int i = blockIdx.x * 256 + threadIdx.x;
    if (i < e) atomicAdd(&cnt[dst[i]], 1);
}

__global__ void scan_kernel(const int* __restrict__ cnt, int* __restrict__ offs,
                            int* __restrict__ cursor, int n) {
    __shared__ int sums[256];
    int t = threadIdx.x;
    int chunk = (n + 255) >> 8;
    int lo = t * chunk;
    int hi = min(lo + chunk, n);
    int s = 0;
    for (int i = lo; i < hi; ++i) s += cnt[i];
    sums[t] = s;
    __syncthreads();
    if (t == 0) {
        int run = 0;
        for (int i = 0; i < 256; ++i) { int v = sums[i]; sums[i] = run; run += v; }
    }
    __syncthreads();
    int run = sums[t];
    for (int i = lo; i < hi; ++i) { int v = cnt[i]; offs[i] = run; cursor[i] = run; run += v; }
    if (t == 255) offs[n] = run;
}

__global__ void scatter_kernel(const int* __restrict__ src, const int* __restrict__ dst,
                               int* __restrict__ cursor, int* __restrict__ src_csr, int e) {
    int i = blockIdx.x * 256 + threadIdx.x;
    if (i < e) {
        int p = atomicAdd(&cursor[dst[i]], 1);
        src_csr[p] = src[i];
    }
}

// ---------------- MFMA GEMM + fused el/er epilogue ----------------
// C[n,M] = A[n,K] @ W[K,M]; block 256 = 4 waves; wave = 16 rows x 64 cols;
// grid (M/64, ceil(n/64)). After the K loop, dot the fp32 acc tile with al/ar
// for this column tile, shfl-reduce across the 16 m-lanes, atomicAdd into
// el/er[row*2+h]. Column tiles never straddle the head boundary (O%64==0).
template <int K, int M, int O>
__global__ void gemm_mfma(const bf16_t* __restrict__ A, const bf16_t* __restrict__ Wf,
                          bf16_t* __restrict__ C,
                          const bf16_t* __restrict__ al, const bf16_t* __restrict__ ar,
                          float* __restrict__ el, float* __restrict__ er, int n) {
    int w = threadIdx.x >> 6, lane = threadIdx.x & 63;
    int q = lane >> 4, m16 = lane & 15;
    int rf = blockIdx.y * 64 + w * 16;
    if (rf >= n) return;               // n % 16 == 0; kernel has no barriers
    constexpr int KS = K / 32;
    f32x4 acc[4] = {};
    const bf16_t* Arow = A + (size_t)(rf + m16) * K + q * 8;
    for (int ks = 0; ks < KS; ++ks) {
        short8 af = *(const short8*)(Arow + ks * 32);
#pragma unroll
        for (int f = 0; f < 4; ++f) {
            int ct = blockIdx.x * 4 + f;
            short8 bfr = *(const short8*)(Wf + ((size_t)(ct * KS + ks) * 64 + lane) * 8);
            acc[f] = __builtin_amdgcn_mfma_f32_16x16x32_bf16(af, bfr, acc[f], 0, 0, 0);
        }
    }
    int col0 = blockIdx.x * 64;
    // --- C store ---
#pragma unroll
    for (int f = 0; f < 4; ++f) {
#pragma unroll
        for (int r = 0; r < 4; ++r) {
            int row = rf + q * 4 + r;
            C[(size_t)row * M + col0 + f * 16 + m16] = f2bf(acc[f][r]);
        }
    }
    // --- el/er partials for this 64-col tile ---
    int h = (col0 >= O) ? 1 : 0;
    const bf16_t* alh = al + h * O + (col0 - h * O);
    const bf16_t* arh = ar + h * O + (col0 - h * O);
    float alf[4], arf[4];
#pragma unroll
    for (int f = 0; f < 4; ++f) {
        alf[f] = bf2f(alh[f * 16 + m16]);
        arf[f] = bf2f(arh[f * 16 + m16]);
    }
    float pel[4] = {}, per2[4] = {};
#pragma unroll
    for (int f = 0; f < 4; ++f) {
#pragma unroll
        for (int r = 0; r < 4; ++r) {
            pel[r] += acc[f][r] * alf[f];
            per2[r] += acc[f][r] * arf[f];
        }
    }
#pragma unroll
    for (int off = 1; off < 16; off <<= 1) {
#pragma unroll
        for (int r = 0; r < 4; ++r) {
            pel[r] += __shfl_xor(pel[r], off);
            per2[r] += __shfl_xor(per2[r], off);
        }
    }
    if (m16 == 0) {
#pragma unroll
        for (int r = 0; r < 4; ++r) {
            int row = rf + q * 4 + r;
            atomicAdd(&el[row * 2 + h], pel[r]);
            atomicAdd(&er[row * 2 + h], per2[r]);
        }
    }
}

// ---------------- fused softmax + aggregate ----------------
// One dst per block, 256 threads = 4 waves.
// Phase 1: per-thread online (m,s) over strided edges for 4 (rel,head) pairs,
//          wave butterfly merge, cross-wave LDS merge -> fin_m / fin_inv.
// Phase 2: wave w strides edges, recomputes alpha inline, gathers full rows;
//          partials merged in LDS; bias + head-mean (+relu / final store).
template <int O, bool FINAL>
__global__ void agg_fused3(
    const int* __restrict__ offs0, const int* __restrict__ srcc0,
    const float* __restrict__ el0, const float* __restrict__ er0,
    const bf16_t* __restrict__ feat0,
    const int* __restrict__ offs1, const int* __restrict__ srcc1,
    const float* __restrict__ el1, const float* __restrict__ er1,
    const bf16_t* __restrict__ feat1,
    const bf16_t* __restrict__ b0, const bf16_t* __restrict__ b1,
    void* __restrict__ out, const int* __restrict__ flag) {
    constexpr int VD = (2 * O) / 128;     // dwords per lane: 4 (O=256) / 2 (O=128)
    __shared__ float sh[4][2 * O];
    __shared__ float red_m[4][4], red_s[4][4];
    __shared__ float fin_m[4], fin_inv[4];
    int d = blockIdx.x;
    int t = threadIdx.x;
    int w = t >> 6, lane = t & 63;

    // ---- phase 1: online softmax stats ----
    float tm[4] = {-1e30f, -1e30f, -1e30f, -1e30f};
    float ts[4] = {0.f, 0.f, 0.f, 0.f};
    int beg0 = offs0[d], end0 = offs0[d + 1];
    int beg1 = offs1[d], end1 = offs1[d + 1];
    float er0h0 = er0[d * 2], er0h1 = er0[d * 2 + 1];
    float er1h0 = er1[d * 2], er1h1 = er1[d * 2 + 1];
    for (int j = beg0 + t; j < end0; j += 256) {
        int s = srcc0[j];
        float2 ev = ((const float2*)el0)[s];
        float e0 = lrelu(ev.x + er0h0);
        float e1 = lrelu(ev.y + er0h1);
        float mn = fmaxf(tm[0], e0);
        ts[0] = ts[0] * __expf(tm[0] - mn) + __expf(e0 - mn); tm[0] = mn;
        mn = fmaxf(tm[1], e1);
        ts[1] = ts[1] * __expf(tm[1] - mn) + __expf(e1 - mn); tm[1] = mn;
    }
    for (int j = beg1 + t; j < end1; j += 256) {
        int s = srcc1[j];
        float2 ev = ((const float2*)el1)[s];
        float e0 = lrelu(ev.x + er1h0);
        float e1 = lrelu(ev.y + er1h1);
        float mn = fmaxf(tm[2], e0);
        ts[2] = ts[2] * __expf(tm[2] - mn) + __expf(e0 - mn); tm[2] = mn;
        mn = fmaxf(tm[3], e1);
        ts[3] = ts[3] * __expf(tm[3] - mn) + __expf(e1 - mn); tm[3] = mn;
    }
#pragma unroll
    for (int off = 1; off < 64; off <<= 1) {
#pragma unroll
        for (int k = 0; k < 4; ++k) {
            float om = __shfl_xor(tm[k], off);
            float os = __shfl_xor(ts[k], off);
            float mn = fmaxf(tm[k], om);
            ts[k] = ts[k] * __expf(tm[k] - mn) + os * __expf(om - mn);
            tm[k] = mn;
        }
    }
    if (lane == 0) {
#pragma unroll
        for (int k = 0; k < 4; ++k) { red_m[w][k] = tm[k]; red_s[w][k] = ts[k]; }
    }
    __syncthreads();
    if (t < 4) {
        float m = -1e30f, s = 0.f;
#pragma unroll
        for (int ww = 0; ww < 4; ++ww) {
            float om = red_m[ww][t], os = red_s[ww][t];
            float mn = fmaxf(m, om);
            s = s * __expf(m - mn) + os * __expf(om - mn);
            m = mn;
        }
        fin_m[t] = m;
        fin_inv[t] = 1.f / fmaxf(s, 1e-9f);
    }
    __syncthreads();

    // ---- phase 2: gather ----
    int head = lane >> 5;                 // lanes 0-31 = head 0 dims, 32-63 = head 1
    float acc[2 * VD];
#pragma unroll
    for (int k = 0; k < 2 * VD; ++k) acc[k] = 0.f;
    {
        float erh = head ? er0h1 : er0h0;
        float fmh = head ? fin_m[1] : fin_m[0];
        float fih = head ? fin_inv[1] : fin_inv[0];
        const unsigned* fp = (const unsigned*)feat0;
        for (int j = beg0 + w; j < end0; j += 4) {
            int s = srcc0[j];
            float2 ev = ((const float2*)el0)[s];
            float e = lrelu((head ? ev.y : ev.x) + erh);
            float a = __expf(e - fmh) * fih;
            const unsigned* p = fp + (size_t)s * O + lane * VD;
            if constexpr (VD == 4) {
                uint4 pk = *(const uint4*)p;
                acc[0] += a * bf2f((bf16_t)(pk.x & 0xffffu));
                acc[1] += a * bf2f((bf16_t)(pk.x >> 16));
                acc[2] += a * bf2f((bf16_t)(pk.y & 0xffffu));
                acc[3] += a * bf2f((bf16_t)(pk.y >> 16));
                acc[4] += a * bf2f((bf16_t)(pk.z & 0xffffu));
                acc[5] += a * bf2f((bf16_t)(pk.z >> 16));
                acc[6] += a * bf2f((bf16_t)(pk.w & 0xffffu));
                acc[7] += a * bf2f((bf16_t)(pk.w >> 16));
            } else {
                uint2 pk = *(const uint2*)p;
                acc[0] += a * bf2f((bf16_t)(pk.x & 0xffffu));
                acc[1] += a * bf2f((bf16_t)(pk.x >> 16));
                acc[2] += a * bf2f((bf16_t)(pk.y & 0xffffu));
                acc[3] += a * bf2f((bf16_t)(pk.y >> 16));
            }
        }
    }
    {
        float erh = head ? er1h1 : er1h0;
        float fmh = head ? fin_m[3] : fin_m[2];
        float fih = head ? fin_inv[3] : fin_inv[2];
        const unsigned* fp = (const unsigned*)feat1;
        for (int j = beg1 + w; j < end1; j += 4) {
            int s = srcc1[j];
            float2 ev = ((const float2*)el1)[s];
            float e = lrelu((head ? ev.y : ev.x) + erh);
            float a = __expf(e - fmh) * fih;
            const unsigned* p = fp + (size_t)s * O + lane * VD;
            if constexpr (VD == 4) {
                uint4 pk = *(const uint4*)p;
                acc[0] += a * bf2f((bf16_t)(pk.x & 0xffffu));
                acc[1] += a * bf2f((bf16_t)(pk.x >> 16));
                acc[2] += a * bf2f((bf16_t)(pk.y & 0xffffu));
                acc[3] += a * bf2f((bf16_t)(pk.y >> 16));
                acc[4] += a * bf2f((bf16_t)(pk.z & 0xffffu));
                acc[5] += a * bf2f((bf16_t)(pk.z >> 16));
                acc[6] += a * bf2f((bf16_t)(pk.w & 0xffffu));
                acc[7] += a * bf2f((bf16_t)(pk.w >> 16));
            } else {
                uint2 pk = *(const uint2*)p;
                acc[0] += a * bf2f((bf16_t)(pk.x & 0xffffu));
                acc[1] += a * bf2f((bf16_t)(pk.x >> 16));
                acc[2] += a * bf2f((bf16_t)(pk.y & 0xffffu));
                acc[3] += a * bf2f((bf16_t)(pk.y >> 16));
            }
        }
    }
#pragma unroll
    for (int k = 0; k < 2 * VD; ++k) sh[w][lane * (2 * VD) + k] = acc[k];
    __syncthreads();
    int o = t;
    if (o < O) {
        float v = 0.f;
#pragma unroll
        for (int ww = 0; ww < 4; ++ww) v += sh[ww][o] + sh[ww][o + O];
        v += bf2f(b0[o]) + bf2f(b0[O + o]) + bf2f(b1[o]) + bf2f(b1[O + o]);
        v *= 0.5f;
        if (!FINAL) {
            ((bf16_t*)out)[(size_t)d * O + o] = f2bf(fmaxf(v, 0.f));
        } else {
            if (*flag) ((float*)out)[(size_t)d * O + o] = v;
            else       ((bf16_t*)out)[(size_t)d * O + o] = f2bf(v);
        }
    }
}

extern "C" void kernel_launch(void* const* d_in, const int* in_sizes, int n_in,
                              void* d_out, int out_size, void* d_ws, size_t ws_size,
                              hipStream_t stream) {
    (void)in_sizes; (void)n_in; (void)out_size; (void)ws_size;
    const int* src0 = (const int*)d_in[1];
    const int* dst0 = (const int*)d_in[2];
    const int* src1 = (const int*)d_in[3];
    const int* dst1 = (const int*)d_in[4];

    char* ws = (char*)d_ws;
    size_t off = 0;
    auto alloc = [&](size_t bytes) -> void* {
        void* p = ws + off;
        off = (off + bytes + 255) & ~(size_t)255;
        return p;
    };
    int* flag = (int*)alloc(4);
    static const int tn[NT] = {NN * 128,
                               128 * 512, 512, 512, 512,
                               128 * 512, 512, 512, 512,
                               256 * 256, 256, 256, 256,
                               256 * 256, 256, 256, 256};
    bf16_t* tb[NT];
    for (int i = 0; i < NT; ++i) tb[i] = (bf16_t*)alloc((size_t)tn[i] * 2);
    bf16_t* xb    = tb[0];
    bf16_t* al1_0b = tb[2],  *ar1_0b = tb[3],  *b1_0b = tb[4];
    bf16_t* al1_1b = tb[6],  *ar1_1b = tb[7],  *b1_1b = tb[8];
    bf16_t* al2_0b = tb[10], *ar2_0b = tb[11], *b2_0b = tb[12];
    bf16_t* al2_1b = tb[14], *ar2_1b = tb[15], *b2_1b = tb[16];

    bf16_t* Wf[4];
    for (int i = 0; i < 4; ++i) Wf[i] = (bf16_t*)alloc((size_t)65536 * 2);

    int*    cnt0  = (int*)alloc(NN * 4);
    int*    cnt1  = (int*)alloc(NN * 4);
    int*    offs0 = (int*)alloc((NN + 1) * 4);
    int*    offs1 = (int*)alloc((NN + 1) * 4);
    int*    cur0  = (int*)alloc(NN * 4);
    int*    cur1  = (int*)alloc(NN * 4);
    int*    srcc0 = (int*)alloc(NE * 4);
    int*    srcc1 = (int*)alloc(NE * 4);
    float*  el0   = (float*)alloc(NN * 2 * 4);
    float*  er0   = (float*)alloc(NN * 2 * 4);
    float*  el1   = (float*)alloc(NN * 2 * 4);
    float*  er1   = (float*)alloc(NN * 2 * 4);
    bf16_t* featA = (bf16_t*)alloc((size_t)NN * 512 * 2);
    bf16_t* featB = (bf16_t*)alloc((size_t)NN * 512 * 2);
    bf16_t* h1    = (bf16_t*)alloc((size_t)NN * 256 * 2);

    // dtype detect + normalize
    detect_kernel<<<1, 1, 0, stream>>>((const unsigned*)d_in[0], flag);
    ConvArgs ca;
    static const int din_idx[NT] = {0, 5, 6, 7, 8, 9, 10, 11, 12,
                                    13, 14, 15, 16, 17, 18, 19, 20};
    int maxn = 0;
    for (int i = 0; i < NT; ++i) {
        ca.src[i] = d_in[din_idx[i]];
        ca.dst[i] = tb[i];
        ca.n[i] = tn[i];
        if (tn[i] > maxn) maxn = tn[i];
    }
    convert_kernel<<<dim3((maxn + 255) / 256, NT), 256, 0, stream>>>(ca, flag);

    // weight repack to MFMA B-frag order (after convert)
    RepackArgs ra;
    ra.src[0] = tb[1];  ra.K[0] = 128; ra.M[0] = 512;   // W1_0
    ra.src[1] = tb[5];  ra.K[1] = 128; ra.M[1] = 512;   // W1_1
    ra.src[2] = tb[9];  ra.K[2] = 256; ra.M[2] = 256;   // W2_0
    ra.src[3] = tb[13]; ra.K[3] = 256; ra.M[3] = 256;   // W2_1
    for (int i = 0; i < 4; ++i) ra.dst[i] = Wf[i];
    repack_kernel<<<dim3(32, 4), 256, 0, stream>>>(ra);

    const int EB = (NE + 255) / 256;
    const int NB = (NN + 255) / 256;
    const int ZB = (NN * 2 + 255) / 256;

    // CSR build (shared by both layers)
    zero_i32<<<NB, 256, 0, stream>>>(cnt0, NN);
    zero_i32<<<NB, 256, 0, stream>>>(cnt1, NN);
    hist_kernel<<<EB, 256, 0, stream>>>(dst0, cnt0, NE);
    hist_kernel<<<EB, 256, 0, stream>>>(dst1, cnt1, NE);
    scan_kernel<<<1, 256, 0, stream>>>(cnt0, offs0, cur0, NN);
    scan_kernel<<<1, 256, 0, stream>>>(cnt1, offs1, cur1, NN);
    scatter_kernel<<<EB, 256, 0, stream>>>(src0, dst0, cur0, srcc0, NE);
    scatter_kernel<<<EB, 256, 0, stream>>>(src1, dst1, cur1, srcc1, NE);

    // ---- Layer 1: K=128, M=512, O=256/head ----
    zero_elr<<<ZB, 256, 0, stream>>>(el0, er0, el1, er1, NN * 2);
    gemm_mfma<128, 512, 256><<<dim3(8, 313), 256, 0, stream>>>(
        xb, Wf[0], featA, al1_0b, ar1_0b, el0, er0, NN);
    gemm_mfma<128, 512, 256><<<dim3(8, 313), 256, 0, stream>>>(
        xb, Wf[1], featB, al1_1b, ar1_1b, el1, er1, NN);
    agg_fused3<256, false><<<NN, 256, 0, stream>>>(
        offs0, srcc0, el0, er0, featA, offs1, srcc1, el1, er1, featB,
        b1_0b, b1_1b, h1, flag);

    // ---- Layer 2: K=256, M=256, O=128/head ----
    zero_elr<<<ZB, 256, 0, stream>>>(el0, er0, el1, er1, NN * 2);
    gemm_mfma<256, 256, 128><<<dim3(4, 313), 256, 0, stream>>>(
        h1, Wf[2], featA, al2_0b, ar2_0b, el0, er0, NN);
    gemm_mfma<256, 256, 128><<<dim3(4, 313), 256, 0, stream>>>(
        h1, Wf[3], featB, al2_1b, ar2_1b, el1, er1, NN);
    agg_fused3<128, true><<<NN, 256, 0, stream>>>(
        offs0, srcc0, el0, er0, featA, offs1, srcc1, el1, er1, featB,
        b2_0b, b2_1b, d_out, flag);
}

// Round 5
// 488.572 us; speedup vs baseline: 2.3303x; 1.2517x over previous
//
#include <hip/hip_runtime.h>

// RGAT: 2-layer, 2-relation GAT. N=20000, E=320000/rel, D=128, H=2.
// Round 5: (1) agg: softmax alpha precomputed once per block into LDS
// (phase 1a stage logits, 1b wave-parallel online-softmax, 1c e->alpha);
// hot gather loop has zero exp / zero el traffic. (2) dispatch count 17->11
// via merged CSR kernels (grid.y=2), merged per-relation GEMMs (grid.z=2),
// single upfront zero kernel covering cnt + all 8 el/er buffers.

#define NN 20000
#define NE 320000

typedef unsigned short bf16_t;
typedef __attribute__((ext_vector_type(8))) short short8;
typedef __attribute__((ext_vector_type(4))) float f32x4;

__device__ __forceinline__ float bf2f(bf16_t u) {
    return __uint_as_float(((unsigned)u) << 16);
}
__device__ __forceinline__ bf16_t f2bf(float f) {
    unsigned x = __float_as_uint(f);
    unsigned r = (x + 0x7fffu + ((x >> 16) & 1u)) >> 16;   // RNE
    return (bf16_t)r;
}
__device__ __forceinline__ float lrelu(float v) {
    return (v > 0.f) ? v : 0.2f * v;
}

// ---------------- dtype detection (fp32 vs bf16 source) ----------------
__global__ void detect_kernel(const unsigned* __restrict__ x, int* __restrict__ flag) {
    int lane = threadIdx.x;   // 64
    float mx = 0.f;
    for (int i = lane; i < 256; i += 64) {
        float v = fabsf(bf2f((bf16_t)(x[i] & 0xffffu)));
        v = (v <= 1e30f) ? v : 1e30f;   // NaN/inf encodings -> decisive large
        mx = fmaxf(mx, v);
    }
    for (int off = 32; off > 0; off >>= 1) mx = fmaxf(mx, __shfl_xor(mx, off));
    if (lane == 0) *flag = (mx > 1e6f) ? 1 : 0;   // 1 = fp32 source
}

// ---------------- batched conversion of all float tensors to bf16 ----
#define NT 17
struct ConvArgs {
    const void* src[NT];
    bf16_t* dst[NT];
    int n[NT];
};
__global__ void convert_kernel(ConvArgs a, const int* __restrict__ flag) {
    int ti = blockIdx.y;
    int n = a.n[ti];
    int i = blockIdx.x * 256 + threadIdx.x;
    if (i >= n) return;
    if (*flag) a.dst[ti][i] = f2bf(((const float*)a.src[ti])[i]);
    else       a.dst[ti][i] = ((const bf16_t*)a.src[ti])[i];
}

// ---------------- weight repack: row-major W[K,M] -> MFMA B-frag order ------
struct RepackArgs {
    const bf16_t* src[4];
    bf16_t* dst[4];
    int K[4];
    int M[4];
};
__global__ void repack_kernel(RepackArgs ra) {
    int wi = blockIdx.y;
    const bf16_t* W = ra.src[wi];
    bf16_t* Wf = ra.dst[wi];
    int K = ra.K[wi], M = ra.M[wi];
    int i = blockIdx.x * 256 + threadIdx.x;          // (ct*KS+ks)*64 + lane
    int total = (M >> 4) * (K >> 5) * 64;
    if (i >= total) return;
    int lane = i & 63;
    int t = i >> 6;
    int KS = K >> 5;
    int ct = t / KS, ks = t - ct * KS;
    int kbase = ks * 32 + (lane >> 4) * 8;
    int col = ct * 16 + (lane & 15);
    bf16_t* out = Wf + (size_t)i * 8;
#pragma unroll
    for (int j = 0; j < 8; ++j) out[j] = W[(size_t)(kbase + j) * M + col];
}

// ---------------- zero a contiguous int region ----------------
__global__ void zero_range(int* __restrict__ p, int n) {
    int i = blockIdx.x * 256 + threadIdx.x;
    if (i < n) p[i] = 0;
}

// ---------------- CSR build (both relations per launch) ----------------
struct Csr2 {
    const int* src[2];
    const int* dst[2];
    int* cnt[2];
    int* offs[2];
    int* cursor[2];
    int* srcc[2];
};
__global__ void hist2_kernel(Csr2 c, int e) {
    int rel = blockIdx.y;
    int i = blockIdx.x * 256 + threadIdx.x;
    if (i < e) atomicAdd(&c.cnt[rel][c.dst[rel][i]], 1);
}
__global__ void scan2_kernel(Csr2 c, int n) {
    int rel = blockIdx.x;
    const int* cnt = c.cnt[rel];
    int* offs = c.offs[rel];
    int* cursor = c.cursor[rel];
    __shared__ int sums[256];
    int t = threadIdx.x;
    int chunk = (n + 255) >> 8;
    int lo = t * chunk;
    int hi = min(lo + chunk, n);
    int s = 0;
    for (int i = lo; i < hi; ++i) s += cnt[i];
    sums[t] = s;
    __syncthreads();
    if (t == 0) {
        int run = 0;
        for (int i = 0; i < 256; ++i) { int v = sums[i]; sums[i] = run; run += v; }
    }
    __syncthreads();
    int run = sums[t];
    for (int i = lo; i < hi; ++i) { int v = cnt[i]; offs[i] = run; cursor[i] = run; run += v; }
    if (t == 255) offs[n] = run;
}
__global__ void scatter2_kernel(Csr2 c, int e) {
    int rel = blockIdx.y;
    int i = blockIdx.x * 256 + threadIdx.x;
    if (i < e) {
        int p = atomicAdd(&c.cursor[rel][c.dst[rel][i]], 1);
        c.srcc[rel][p] = c.src[rel][i];
    }
}

// ---------------- MFMA GEMM (both relations, grid.z=2) + el/er epilogue -----
// C[n,M] = A[n,K] @ W[K,M]; block 256 = 4 waves; wave = 16 rows x 64 cols;
// grid (M/64, ceil(n/64), 2). Epilogue dots fp32 acc with al/ar, shfl-reduces
// across 16 m-lanes, atomicAdd into el/er[row*2+h]. 64-col tiles never
// straddle the head boundary (O % 64 == 0).
struct GemmPair {
    const bf16_t* Wf[2];
    bf16_t* C[2];
    const bf16_t* al[2];
    const bf16_t* ar[2];
    float* el[2];
    float* er[2];
};
template <int K, int M, int O>
__global__ void gemm_mfma2(const bf16_t* __restrict__ A, GemmPair g, int n) {
    int rel = blockIdx.z;
    const bf16_t* Wf = g.Wf[rel];
    bf16_t* C = g.C[rel];
    int w = threadIdx.x >> 6, lane = threadIdx.x & 63;
    int q = lane >> 4, m16 = lane & 15;
    int rf = blockIdx.y * 64 + w * 16;
    if (rf >= n) return;               // n % 16 == 0; kernel has no barriers
    constexpr int KS = K / 32;
    f32x4 acc[4] = {};
    const bf16_t* Arow = A + (size_t)(rf + m16) * K + q * 8;
    for (int ks = 0; ks < KS; ++ks) {
        short8 af = *(const short8*)(Arow + ks * 32);
#pragma unroll
        for (int f = 0; f < 4; ++f) {
            int ct = blockIdx.x * 4 + f;
            short8 bfr = *(const short8*)(Wf + ((size_t)(ct * KS + ks) * 64 + lane) * 8);
            acc[f] = __builtin_amdgcn_mfma_f32_16x16x32_bf16(af, bfr, acc[f], 0, 0, 0);
        }
    }
    int col0 = blockIdx.x * 64;
#pragma unroll
    for (int f = 0; f < 4; ++f) {
#pragma unroll
        for (int r = 0; r < 4; ++r) {
            int row = rf + q * 4 + r;
            C[(size_t)row * M + col0 + f * 16 + m16] = f2bf(acc[f][r]);
        }
    }
    int h = (col0 >= O) ? 1 : 0;
    const bf16_t* alh = g.al[rel] + h * O + (col0 - h * O);
    const bf16_t* arh = g.ar[rel] + h * O + (col0 - h * O);
    float alf[4], arf[4];
#pragma unroll
    for (int f = 0; f < 4; ++f) {
        alf[f] = bf2f(alh[f * 16 + m16]);
        arf[f] = bf2f(arh[f * 16 + m16]);
    }
    float pel[4] = {}, per2[4] = {};
#pragma unroll
    for (int f = 0; f < 4; ++f) {
#pragma unroll
        for (int r = 0; r < 4; ++r) {
            pel[r] += acc[f][r] * alf[f];
            per2[r] += acc[f][r] * arf[f];
        }
    }
#pragma unroll
    for (int off = 1; off < 16; off <<= 1) {
#pragma unroll
        for (int r = 0; r < 4; ++r) {
            pel[r] += __shfl_xor(pel[r], off);
            per2[r] += __shfl_xor(per2[r], off);
        }
    }
    if (m16 == 0) {
#pragma unroll
        for (int r = 0; r < 4; ++r) {
            int row = rf + q * 4 + r;
            atomicAdd(&g.el[rel][row * 2 + h], pel[r]);
            atomicAdd(&g.er[rel][row * 2 + h], per2[r]);
        }
    }
}

// ---------------- fused softmax + aggregate (LDS alpha) ----------------
// One dst per block, 256 threads = 4 waves.
// 1a: stage src-ids + raw leaky-relu logits into LDS (1 el-gather per edge).
// 1b: waves 0,1 (rel 0,1): per-(head) online (m,s) over LDS, 5-level shfl merge.
// 1c: all threads convert e -> alpha in LDS (1 exp per (edge,head)).
// 2:  wave-strided full-row gather, alpha/src from LDS broadcast; LDS merge;
//     bias + head-mean (+relu / final store).
template <int O, bool FINAL>
__global__ void agg_fused4(
    const int* __restrict__ offs0, const int* __restrict__ srcc0,
    const float* __restrict__ el0, const float* __restrict__ er0,
    const bf16_t* __restrict__ feat0,
    const int* __restrict__ offs1, const int* __restrict__ srcc1,
    const float* __restrict__ el1, const float* __restrict__ er1,
    const bf16_t* __restrict__ feat1,
    const bf16_t* __restrict__ b0, const bf16_t* __restrict__ b1,
    void* __restrict__ out, const int* __restrict__ flag) {
    constexpr int VD = (2 * O) / 128;     // dwords per lane: 4 (O=256) / 2 (O=128)
    constexpr int CAP = 192;              // edges/rel staged in LDS (max deg ~45)
    __shared__ float sh[4][2 * O];
    __shared__ int   ss[2][CAP];
    __shared__ float se[2][2 * CAP];
    __shared__ float fin_m[4], fin_inv[4];
    int d = blockIdx.x;
    int t = threadIdx.x;
    int w = t >> 6, lane = t & 63;
    int beg0 = offs0[d], deg0 = offs0[d + 1] - beg0;
    int beg1 = offs1[d], deg1 = offs1[d + 1] - beg1;
    int c0 = min(deg0, CAP), c1 = min(deg1, CAP);
    float er00 = er0[d * 2], er01 = er0[d * 2 + 1];
    float er10 = er1[d * 2], er11 = er1[d * 2 + 1];

    // ---- 1a: stage ----
    for (int j = t; j < c0; j += 256) {
        int s = srcc0[beg0 + j];
        ss[0][j] = s;
        float2 ev = ((const float2*)el0)[s];
        se[0][2 * j] = lrelu(ev.x + er00);
        se[0][2 * j + 1] = lrelu(ev.y + er01);
    }
    for (int j = t; j < c1; j += 256) {
        int s = srcc1[beg1 + j];
        ss[1][j] = s;
        float2 ev = ((const float2*)el1)[s];
        se[1][2 * j] = lrelu(ev.x + er10);
        se[1][2 * j + 1] = lrelu(ev.y + er11);
    }
    __syncthreads();

    // ---- 1b: online softmax stats, wave w handles relation w ----
    if (w < 2) {
        int rel = w;
        int head = lane & 1;
        int cc = rel ? c1 : c0;
        int deg = rel ? deg1 : deg0;
        int beg = rel ? beg1 : beg0;
        const int* sc = rel ? srcc1 : srcc0;
        const float* elp = rel ? el1 : el0;
        float erh = rel ? (head ? er11 : er10) : (head ? er01 : er00);
        float m = -1e30f, s = 0.f;
        for (int j = lane >> 1; j < cc; j += 32) {
            float e = se[rel][2 * j + head];
            float mn = fmaxf(m, e);
            s = s * __expf(m - mn) + __expf(e - mn);
            m = mn;
        }
        for (int j = cc + (lane >> 1); j < deg; j += 32) {   // overflow (cold)
            int sv = sc[beg + j];
            float e = lrelu(elp[sv * 2 + head] + erh);
            float mn = fmaxf(m, e);
            s = s * __expf(m - mn) + __expf(e - mn);
            m = mn;
        }
#pragma unroll
        for (int off = 2; off < 64; off <<= 1) {
            float om = __shfl_xor(m, off);
            float os = __shfl_xor(s, off);
            float mn = fmaxf(m, om);
            s = s * __expf(m - mn) + os * __expf(om - mn);
            m = mn;
        }
        if (lane < 2) {
            fin_m[rel * 2 + head] = m;
            fin_inv[rel * 2 + head] = 1.f / fmaxf(s, 1e-9f);
        }
    }
    __syncthreads();

    // ---- 1c: e -> alpha ----
    for (int i = t; i < 2 * c0; i += 256)
        se[0][i] = __expf(se[0][i] - fin_m[i & 1]) * fin_inv[i & 1];
    for (int i = t; i < 2 * c1; i += 256)
        se[1][i] = __expf(se[1][i] - fin_m[2 + (i & 1)]) * fin_inv[2 + (i & 1)];
    __syncthreads();

    // ---- 2: gather ----
    int head = lane >> 5;                 // lanes 0-31 = head 0, 32-63 = head 1
    float acc[2 * VD];
#pragma unroll
    for (int k = 0; k < 2 * VD; ++k) acc[k] = 0.f;
    {
        const unsigned* fp = (const unsigned*)feat0;
        for (int jj = w; jj < deg0; jj += 4) {
            int s;
            float a;
            if (jj < CAP) {
                s = ss[0][jj];
                a = se[0][2 * jj + head];
            } else {                       // cold fallback
                s = srcc0[beg0 + jj];
                float e = lrelu(el0[s * 2 + head] + (head ? er01 : er00));
                a = __expf(e - fin_m[head]) * fin_inv[head];
            }
            const unsigned* p = fp + (size_t)s * O + lane * VD;
            if constexpr (VD == 4) {
                uint4 pk = *(const uint4*)p;
                acc[0] += a * bf2f((bf16_t)(pk.x & 0xffffu));
                acc[1] += a * bf2f((bf16_t)(pk.x >> 16));
                acc[2] += a * bf2f((bf16_t)(pk.y & 0xffffu));
                acc[3] += a * bf2f((bf16_t)(pk.y >> 16));
                acc[4] += a * bf2f((bf16_t)(pk.z & 0xffffu));
                acc[5] += a * bf2f((bf16_t)(pk.z >> 16));
                acc[6] += a * bf2f((bf16_t)(pk.w & 0xffffu));
                acc[7] += a * bf2f((bf16_t)(pk.w >> 16));
            } else {
                uint2 pk = *(const uint2*)p;
                acc[0] += a * bf2f((bf16_t)(pk.x & 0xffffu));
                acc[1] += a * bf2f((bf16_t)(pk.x >> 16));
                acc[2] += a * bf2f((bf16_t)(pk.y & 0xffffu));
                acc[3] += a * bf2f((bf16_t)(pk.y >> 16));
            }
        }
    }
    {
        const unsigned* fp = (const unsigned*)feat1;
        for (int jj = w; jj < deg1; jj += 4) {
            int s;
            float a;
            if (jj < CAP) {
                s = ss[1][jj];
                a = se[1][2 * jj + head];
            } else {
                s = srcc1[beg1 + jj];
                float e = lrelu(el1[s * 2 + head] + (head ? er11 : er10));
                a = __expf(e - fin_m[2 + head]) * fin_inv[2 + head];
            }
            const unsigned* p = fp + (size_t)s * O + lane * VD;
            if constexpr (VD == 4) {
                uint4 pk = *(const uint4*)p;
                acc[0] += a * bf2f((bf16_t)(pk.x & 0xffffu));
                acc[1] += a * bf2f((bf16_t)(pk.x >> 16));
                acc[2] += a * bf2f((bf16_t)(pk.y & 0xffffu));
                acc[3] += a * bf2f((bf16_t)(pk.y >> 16));
                acc[4] += a * bf2f((bf16_t)(pk.z & 0xffffu));
                acc[5] += a * bf2f((bf16_t)(pk.z >> 16));
                acc[6] += a * bf2f((bf16_t)(pk.w & 0xffffu));
                acc[7] += a * bf2f((bf16_t)(pk.w >> 16));
            } else {
                uint2 pk = *(const uint2*)p;
                acc[0] += a * bf2f((bf16_t)(pk.x & 0xffffu));
                acc[1] += a * bf2f((bf16_t)(pk.x >> 16));
                acc[2] += a * bf2f((bf16_t)(pk.y & 0xffffu));
                acc[3] += a * bf2f((bf16_t)(pk.y >> 16));
            }
        }
    }
#pragma unroll
    for (int k = 0; k < 2 * VD; ++k) sh[w][lane * (2 * VD) + k] = acc[k];
    __syncthreads();
    int o = t;
    if (o < O) {
        float v = 0.f;
#pragma unroll
        for (int ww = 0; ww < 4; ++ww) v += sh[ww][o] + sh[ww][o + O];
        v += bf2f(b0[o]) + bf2f(b0[O + o]) + bf2f(b1[o]) + bf2f(b1[O + o]);
        v *= 0.5f;
        if (!FINAL) {
            ((bf16_t*)out)[(size_t)d * O + o] = f2bf(fmaxf(v, 0.f));
        } else {
            if (*flag) ((float*)out)[(size_t)d * O + o] = v;
            else       ((bf16_t*)out)[(size_t)d * O + o] = f2bf(v);
        }
    }
}

extern "C" void kernel_launch(void* const* d_in, const int* in_sizes, int n_in,
                              void* d_out, int out_size, void* d_ws, size_t ws_size,
                              hipStream_t stream) {
    (void)in_sizes; (void)n_in; (void)out_size; (void)ws_size;
    const int* src0 = (const int*)d_in[1];
    const int* dst0 = (const int*)d_in[2];
    const int* src1 = (const int*)d_in[3];
    const int* dst1 = (const int*)d_in[4];

    char* ws = (char*)d_ws;
    size_t off = 0;
    auto alloc = [&](size_t bytes) -> void* {
        void* p = ws + off;
        off = (off + bytes + 255) & ~(size_t)255;
        return p;
    };
    int* flag = (int*)alloc(4);
    static const int tn[NT] = {NN * 128,
                               128 * 512, 512, 512, 512,
                               128 * 512, 512, 512, 512,
                               256 * 256, 256, 256, 256,
                               256 * 256, 256, 256, 256};
    bf16_t* tb[NT];
    for (int i = 0; i < NT; ++i) tb[i] = (bf16_t*)alloc((size_t)tn[i] * 2);
    bf16_t* xb    = tb[0];
    bf16_t* al1_0b = tb[2],  *ar1_0b = tb[3],  *b1_0b = tb[4];
    bf16_t* al1_1b = tb[6],  *ar1_1b = tb[7],  *b1_1b = tb[8];
    bf16_t* al2_0b = tb[10], *ar2_0b = tb[11], *b2_0b = tb[12];
    bf16_t* al2_1b = tb[14], *ar2_1b = tb[15], *b2_1b = tb[16];

    bf16_t* Wf[4];
    for (int i = 0; i < 4; ++i) Wf[i] = (bf16_t*)alloc((size_t)65536 * 2);

    // zero region: cnt0, cnt1, 8 el/er buffers (both layers), contiguous
    char* zbeg = ws + off;
    int* cnt0 = (int*)alloc(NN * 4);
    int* cnt1 = (int*)alloc(NN * 4);
    float* elr[8];                         // L1: el0,er0,el1,er1; L2: el0,er0,el1,er1
    for (int i = 0; i < 8; ++i) elr[i] = (float*)alloc(NN * 2 * 4);
    char* zend = ws + off;
    int zcount = (int)((zend - zbeg) >> 2);

    int*    offs0 = (int*)alloc((NN + 1) * 4);
    int*    offs1 = (int*)alloc((NN + 1) * 4);
    int*    cur0  = (int*)alloc(NN * 4);
    int*    cur1  = (int*)alloc(NN * 4);
    int*    srcc0 = (int*)alloc(NE * 4);
    int*    srcc1 = (int*)alloc(NE * 4);
    bf16_t* featA = (bf16_t*)alloc((size_t)NN * 512 * 2);
    bf16_t* featB = (bf16_t*)alloc((size_t)NN * 512 * 2);
    bf16_t* h1    = (bf16_t*)alloc((size_t)NN * 256 * 2);

    // ---- dtype detect + normalize + repack ----
    detect_kernel<<<1, 64, 0, stream>>>((const unsigned*)d_in[0], flag);
    ConvArgs ca;
    static const int din_idx[NT] = {0, 5, 6, 7, 8, 9, 10, 11, 12,
                                    13, 14, 15, 16, 17, 18, 19, 20};
    int maxn = 0;
    for (int i = 0; i < NT; ++i) {
        ca.src[i] = d_in[din_idx[i]];
        ca.dst[i] = tb[i];
        ca.n[i] = tn[i];
        if (tn[i] > maxn) maxn = tn[i];
    }
    convert_kernel<<<dim3((maxn + 255) / 256, NT), 256, 0, stream>>>(ca, flag);
    RepackArgs ra;
    ra.src[0] = tb[1];  ra.K[0] = 128; ra.M[0] = 512;
    ra.src[1] = tb[5];  ra.K[1] = 128; ra.M[1] = 512;
    ra.src[2] = tb[9];  ra.K[2] = 256; ra.M[2] = 256;
    ra.src[3] = tb[13]; ra.K[3] = 256; ra.M[3] = 256;
    for (int i = 0; i < 4; ++i) ra.dst[i] = Wf[i];
    repack_kernel<<<dim3(32, 4), 256, 0, stream>>>(ra);

    // ---- zero + CSR build ----
    zero_range<<<(zcount + 255) / 256, 256, 0, stream>>>((int*)zbeg, zcount);
    Csr2 cs;
    cs.src[0] = src0; cs.src[1] = src1;
    cs.dst[0] = dst0; cs.dst[1] = dst1;
    cs.cnt[0] = cnt0; cs.cnt[1] = cnt1;
    cs.offs[0] = offs0; cs.offs[1] = offs1;
    cs.cursor[0] = cur0; cs.cursor[1] = cur1;
    cs.srcc[0] = srcc0; cs.srcc[1] = srcc1;
    const int EB = (NE + 255) / 256;
    hist2_kernel<<<dim3(EB, 2), 256, 0, stream>>>(cs, NE);
    scan2_kernel<<<2, 256, 0, stream>>>(cs, NN);
    scatter2_kernel<<<dim3(EB, 2), 256, 0, stream>>>(cs, NE);

    // ---- Layer 1: K=128, M=512, O=256/head ----
    GemmPair g1;
    g1.Wf[0] = Wf[0]; g1.Wf[1] = Wf[1];
    g1.C[0] = featA;  g1.C[1] = featB;
    g1.al[0] = al1_0b; g1.al[1] = al1_1b;
    g1.ar[0] = ar1_0b; g1.ar[1] = ar1_1b;
    g1.el[0] = elr[0]; g1.el[1] = elr[2];
    g1.er[0] = elr[1]; g1.er[1] = elr[3];
    gemm_mfma2<128, 512, 256><<<dim3(8, 313, 2), 256, 0, stream>>>(xb, g1, NN);
    agg_fused4<256, false><<<NN, 256, 0, stream>>>(
        offs0, srcc0, elr[0], elr[1], featA,
        offs1, srcc1, elr[2], elr[3], featB,
        b1_0b, b1_1b, h1, flag);

    // ---- Layer 2: K=256, M=256, O=128/head ----
    GemmPair g2;
    g2.Wf[0] = Wf[2]; g2.Wf[1] = Wf[3];
    g2.C[0] = featA;  g2.C[1] = featB;
    g2.al[0] = al2_0b; g2.al[1] = al2_1b;
    g2.ar[0] = ar2_0b; g2.ar[1] = ar2_1b;
    g2.el[0] = elr[4]; g2.el[1] = elr[6];
    g2.er[0] = elr[5]; g2.er[1] = elr[7];
    gemm_mfma2<256, 256, 128><<<dim3(4, 313, 2), 256, 0, stream>>>(h1, g2, NN);
    agg_fused4<128, true><<<NN, 256, 0, stream>>>(
        offs0, srcc0, elr[4], elr[5], featA,
        offs1, srcc1, elr[6], elr[7], featB,
        b2_0b, b2_1b, d_out, flag);
}

// Round 6
// 466.632 us; speedup vs baseline: 2.4398x; 1.0470x over previous
//
#include <hip/hip_runtime.h>

// RGAT: 2-layer, 2-relation GAT. N=20000, E=320000/rel, D=128, H=2.
// Round 6: aggregation commuted with projection (Sum a*(xW) = (Sum a*x)W):
//   agg1 gathers x rows (256 B/edge, 4x less than feat rows), y1[N,512];
//   h1 = relu(y1 @ Wc1 + bc1) via one MFMA GEMM (head-mean folded into Wc1);
//   el/er via precomputed wal=W@al vectors (L1: GEMV kernel; L2: fused into
//   gemm1 epilogue). agg2 gathers h1 rows -> y2[N,1024]; out = y2 @ Wc2 + bc2.
// featA/featB eliminated; y1/y2 alias one region; flat-grid convert+zero.

#define NN 20000
#define NE 320000

typedef unsigned short bf16_t;
typedef __attribute__((ext_vector_type(8))) short short8;
typedef __attribute__((ext_vector_type(4))) float f32x4;

__device__ __forceinline__ float bf2f(bf16_t u) {
    return __uint_as_float(((unsigned)u) << 16);
}
__device__ __forceinline__ bf16_t f2bf(float f) {
    unsigned x = __float_as_uint(f);
    unsigned r = (x + 0x7fffu + ((x >> 16) & 1u)) >> 16;   // RNE
    return (bf16_t)r;
}
__device__ __forceinline__ float lrelu(float v) {
    return (v > 0.f) ? v : 0.2f * v;
}

// ---------------- dtype detection (fp32 vs bf16 source) ----------------
__global__ void detect_kernel(const unsigned* __restrict__ x, int* __restrict__ flag) {
    int lane = threadIdx.x;   // 64
    float mx = 0.f;
    for (int i = lane; i < 256; i += 64) {
        float v = fabsf(bf2f((bf16_t)(x[i] & 0xffffu)));
        v = (v <= 1e30f) ? v : 1e30f;
        mx = fmaxf(mx, v);
    }
    for (int off = 32; off > 0; off >>= 1) mx = fmaxf(mx, __shfl_xor(mx, off));
    if (lane == 0) *flag = (mx > 1e6f) ? 1 : 0;   // 1 = fp32 source
}

// ------------- flat convert of 17 float tensors to bf16 + zero region -------
#define NT 17
struct CzArgs {
    const void* src[NT];
    bf16_t* dst[NT];
    int n[NT];
    int nblk[NT + 1];     // blocks per segment; last = zero segment
    int* zero_ptr;
    int zn;
};
__global__ void convzero_kernel(CzArgs a, const int* __restrict__ flag) {
    int b = blockIdx.x;
    int ti = 0;
#pragma unroll 1
    for (; ti <= NT; ++ti) {
        if (b < a.nblk[ti]) break;
        b -= a.nblk[ti];
    }
    int i = b * 256 + threadIdx.x;
    if (ti < NT) {
        if (i < a.n[ti]) {
            if (*flag) a.dst[ti][i] = f2bf(((const float*)a.src[ti])[i]);
            else       a.dst[ti][i] = ((const bf16_t*)a.src[ti])[i];
        }
    } else {
        if (i < a.zn) a.zero_ptr[i] = 0;
    }
}

// ---------------- prep: wal/war vectors, combined biases, Wc frag repack ----
struct PrepArgs {
    const bf16_t *W1[2], *W2[2];
    const bf16_t *al1[2], *ar1[2], *al2[2], *ar2[2];
    const bf16_t *b1[2], *b2[2];
    float *wal1, *war1;     // [2rel*2h*128]
    float *wal2, *war2;     // [2rel*2h*256]
    float *bc1, *bc2;       // [256], [128]
    bf16_t *Wc1f, *Wc2f;    // frag-order combined weights
};
// grid: [0,4) wal1/war1 | [4,12) wal2/war2 | [12,14) bc | [14,78) Wc1f | [78,142) Wc2f
__global__ void prep_kernel(PrepArgs p) {
    int bx = blockIdx.x;
    int tid = threadIdx.x;
    if (bx < 4) {                       // wal1/war1: 1024 threads
        int t = bx * 256 + tid;
        int lr = t >> 9, rel = (t >> 8) & 1, h = (t >> 7) & 1, k = t & 127;
        const bf16_t* av = lr ? p.ar1[rel] : p.al1[rel];
        const bf16_t* W = p.W1[rel];
        float s = 0.f;
        for (int o = 0; o < 256; ++o)
            s += bf2f(W[k * 512 + h * 256 + o]) * bf2f(av[h * 256 + o]);
        (lr ? p.war1 : p.wal1)[(rel * 2 + h) * 128 + k] = s;
    } else if (bx < 12) {               // wal2/war2: 2048 threads
        int t = (bx - 4) * 256 + tid;
        int lr = t >> 10, rel = (t >> 9) & 1, h = (t >> 8) & 1, k = t & 255;
        const bf16_t* av = lr ? p.ar2[rel] : p.al2[rel];
        const bf16_t* W = p.W2[rel];
        float s = 0.f;
        for (int o = 0; o < 128; ++o)
            s += bf2f(W[k * 256 + h * 128 + o]) * bf2f(av[h * 128 + o]);
        (lr ? p.war2 : p.wal2)[(rel * 2 + h) * 256 + k] = s;
    } else if (bx < 14) {               // combined biases: 384 threads used
        int t = (bx - 12) * 256 + tid;
        if (t < 256) {
            p.bc1[t] = 0.5f * (bf2f(p.b1[0][t]) + bf2f(p.b1[0][256 + t]) +
                               bf2f(p.b1[1][t]) + bf2f(p.b1[1][256 + t]));
        } else if (t < 384) {
            int o = t - 256;
            p.bc2[o] = 0.5f * (bf2f(p.b2[0][o]) + bf2f(p.b2[0][128 + o]) +
                               bf2f(p.b2[1][o]) + bf2f(p.b2[1][128 + o]));
        }
    } else if (bx < 78) {               // Wc1f repack: K=512, M=256, KS=16
        int i = (bx - 14) * 256 + tid;  // [0, 16384)
        int lane = i & 63;
        int t2 = i >> 6;                // ct*16 + ks
        int ct = t2 >> 4, ks = t2 & 15;
        int col = ct * 16 + (lane & 15);
        bf16_t* out = p.Wc1f + (size_t)i * 8;
#pragma unroll
        for (int j = 0; j < 8; ++j) {
            int r = ks * 32 + ((lane >> 4) << 3) + j;   // [0,512)
            int rel = r >> 8, h = (r >> 7) & 1, kx = r & 127;
            out[j] = f2bf(0.5f * bf2f(p.W1[rel][kx * 512 + h * 256 + col]));
        }
    } else {                            // Wc2f repack: K=1024, M=128, KS=32
        int i = (bx - 78) * 256 + tid;  // [0, 16384)
        int lane = i & 63;
        int t2 = i >> 6;                // ct*32 + ks
        int ct = t2 >> 5, ks = t2 & 31;
        int col = ct * 16 + (lane & 15);
        bf16_t* out = p.Wc2f + (size_t)i * 8;
#pragma unroll
        for (int j = 0; j < 8; ++j) {
            int r = ks * 32 + ((lane >> 4) << 3) + j;   // [0,1024)
            int rel = r >> 9, h = (r >> 8) & 1, kx = r & 255;
            out[j] = f2bf(0.5f * bf2f(p.W2[rel][kx * 256 + h * 128 + col]));
        }
    }
}

// ---------------- CSR build (both relations per launch) ----------------
struct Csr2 {
    const int* src[2];
    const int* dst[2];
    int* cnt[2];
    int* offs[2];
    int* cursor[2];
    int* srcc[2];
};
__global__ void hist2_kernel(Csr2 c, int e) {
    int rel = blockIdx.y;
    int i = blockIdx.x * 256 + threadIdx.x;
    if (i < e) atomicAdd(&c.cnt[rel][c.dst[rel][i]], 1);
}
__global__ void scan2_kernel(Csr2 c, int n) {
    int rel = blockIdx.x;
    const int* cnt = c.cnt[rel];
    int* offs = c.offs[rel];
    int* cursor = c.cursor[rel];
    __shared__ int sums[256];
    int t = threadIdx.x;
    int chunk = (n + 255) >> 8;
    int lo = t * chunk;
    int hi = min(lo + chunk, n);
    int s = 0;
    for (int i = lo; i < hi; ++i) s += cnt[i];
    sums[t] = s;
    __syncthreads();
    if (t == 0) {
        int run = 0;
        for (int i = 0; i < 256; ++i) { int v = sums[i]; sums[i] = run; run += v; }
    }
    __syncthreads();
    int run = sums[t];
    for (int i = lo; i < hi; ++i) { int v = cnt[i]; offs[i] = run; cursor[i] = run; run += v; }
    if (t == 255) offs[n] = run;
}
__global__ void scatter2_kernel(Csr2 c, int e) {
    int rel = blockIdx.y;
    int i = blockIdx.x * 256 + threadIdx.x;
    if (i < e) {
        int p = atomicAdd(&c.cursor[rel][c.dst[rel][i]], 1);
        c.srcc[rel][p] = c.src[rel][i];
    }
}

// ---------------- elr1: el/er for layer 1 via x . wal1 ----------------
// one wave per node; lane covers dims 2l,2l+1; 8 dots via LDS-held vectors.
__global__ void elr1_kernel(const bf16_t* __restrict__ x,
                            const float* __restrict__ wal1, const float* __restrict__ war1,
                            float* __restrict__ el0, float* __restrict__ er0,
                            float* __restrict__ el1, float* __restrict__ er1) {
    __shared__ float wl[512], wr[512];
    int t = threadIdx.x;
    wl[t] = wal1[t]; wl[t + 256] = wal1[t + 256];
    wr[t] = war1[t]; wr[t + 256] = war1[t + 256];
    __syncthreads();
    int w = t >> 6, lane = t & 63;
    int node = blockIdx.x * 4 + w;
    unsigned pk = ((const unsigned*)x)[node * 64 + lane];
    float v0 = bf2f((bf16_t)(pk & 0xffffu));
    float v1 = bf2f((bf16_t)(pk >> 16));
    float de[4], dr[4];
#pragma unroll
    for (int c = 0; c < 4; ++c) {
        de[c] = v0 * wl[c * 128 + 2 * lane % 128 == 0 ? c * 128 + 2 * (lane) : c * 128 + 2 * lane] ;
        de[c] = v0 * wl[c * 128 + 2 * lane] + v1 * wl[c * 128 + 2 * lane + 1];
        dr[c] = v0 * wr[c * 128 + 2 * lane] + v1 * wr[c * 128 + 2 * lane + 1];
    }
    // note: lane in [0,64), dims 2*lane,2*lane+1 in [0,128) ✓
#pragma unroll
    for (int off = 32; off > 0; off >>= 1) {
#pragma unroll
        for (int c = 0; c < 4; ++c) {
            de[c] += __shfl_xor(de[c], off);
            dr[c] += __shfl_xor(dr[c], off);
        }
    }
    if (lane == 0) {
        el0[node * 2 + 0] = de[0]; el0[node * 2 + 1] = de[1];
        el1[node * 2 + 0] = de[2]; el1[node * 2 + 1] = de[3];
        er0[node * 2 + 0] = dr[0]; er0[node * 2 + 1] = dr[1];
        er1[node * 2 + 0] = dr[2]; er1[node * 2 + 1] = dr[3];
    }
}

// ---------------- agg1: softmax + gather x rows -> y1[N,512] ----------------
// one dst per block, 4 waves; softmax phases as round 5; gather = 1 dword/lane
// per edge (x row 256 B), both heads accumulated from one read.
__global__ void agg1_kernel(
    const int* __restrict__ offs0, const int* __restrict__ srcc0,
    const float* __restrict__ el0, const float* __restrict__ er0,
    const int* __restrict__ offs1, const int* __restrict__ srcc1,
    const float* __restrict__ el1, const float* __restrict__ er1,
    const bf16_t* __restrict__ x, bf16_t* __restrict__ y1) {
    constexpr int CAP = 192;
    __shared__ float sh[4][512];
    __shared__ int   ss[2][CAP];
    __shared__ float se[2][2 * CAP];
    __shared__ float fin_m[4], fin_inv[4];
    int d = blockIdx.x;
    int t = threadIdx.x;
    int w = t >> 6, lane = t & 63;
    int beg0 = offs0[d], deg0 = offs0[d + 1] - beg0;
    int beg1 = offs1[d], deg1 = offs1[d + 1] - beg1;
    int c0 = min(deg0, CAP), c1 = min(deg1, CAP);
    float er00 = er0[d * 2], er01 = er0[d * 2 + 1];
    float er10 = er1[d * 2], er11 = er1[d * 2 + 1];

    for (int j = t; j < c0; j += 256) {
        int s = srcc0[beg0 + j];
        ss[0][j] = s;
        float2 ev = ((const float2*)el0)[s];
        se[0][2 * j] = lrelu(ev.x + er00);
        se[0][2 * j + 1] = lrelu(ev.y + er01);
    }
    for (int j = t; j < c1; j += 256) {
        int s = srcc1[beg1 + j];
        ss[1][j] = s;
        float2 ev = ((const float2*)el1)[s];
        se[1][2 * j] = lrelu(ev.x + er10);
        se[1][2 * j + 1] = lrelu(ev.y + er11);
    }
    __syncthreads();
    if (w < 2) {
        int rel = w;
        int head = lane & 1;
        int cc = rel ? c1 : c0;
        int deg = rel ? deg1 : deg0;
        int beg = rel ? beg1 : beg0;
        const int* sc = rel ? srcc1 : srcc0;
        const float* elp = rel ? el1 : el0;
        float erh = rel ? (head ? er11 : er10) : (head ? er01 : er00);
        float m = -1e30f, s = 0.f;
        for (int j = lane >> 1; j < cc; j += 32) {
            float e = se[rel][2 * j + head];
            float mn = fmaxf(m, e);
            s = s * __expf(m - mn) + __expf(e - mn);
            m = mn;
        }
        for (int j = cc + (lane >> 1); j < deg; j += 32) {
            int sv = sc[beg + j];
            float e = lrelu(elp[sv * 2 + head] + erh);
            float mn = fmaxf(m, e);
            s = s * __expf(m - mn) + __expf(e - mn);
            m = mn;
        }
#pragma unroll
        for (int off = 2; off < 64; off <<= 1) {
            float om = __shfl_xor(m, off);
            float os = __shfl_xor(s, off);
            float mn = fmaxf(m, om);
            s = s * __expf(m - mn) + os * __expf(om - mn);
            m = mn;
        }
        if (lane < 2) {
            fin_m[rel * 2 + head] = m;
            fin_inv[rel * 2 + head] = 1.f / fmaxf(s, 1e-9f);
        }
    }
    __syncthreads();
    for (int i = t; i < 2 * c0; i += 256)
        se[0][i] = __expf(se[0][i] - fin_m[i & 1]) * fin_inv[i & 1];
    for (int i = t; i < 2 * c1; i += 256)
        se[1][i] = __expf(se[1][i] - fin_m[2 + (i & 1)]) * fin_inv[2 + (i & 1)];
    __syncthreads();

    const unsigned* xp = (const unsigned*)x;
    float a00 = 0.f, a01 = 0.f, a10 = 0.f, a11 = 0.f;   // rel0: [h][dim]
    float b00 = 0.f, b01 = 0.f, b10 = 0.f, b11 = 0.f;   // rel1
    for (int jj = w; jj < deg0; jj += 4) {
        int s;
        float p0, p1;
        if (jj < CAP) {
            s = ss[0][jj];
            p0 = se[0][2 * jj];
            p1 = se[0][2 * jj + 1];
        } else {
            s = srcc0[beg0 + jj];
            float2 ev = ((const float2*)el0)[s];
            p0 = __expf(lrelu(ev.x + er00) - fin_m[0]) * fin_inv[0];
            p1 = __expf(lrelu(ev.y + er01) - fin_m[1]) * fin_inv[1];
        }
        unsigned pk = xp[s * 64 + lane];
        float v0 = bf2f((bf16_t)(pk & 0xffffu));
        float v1 = bf2f((bf16_t)(pk >> 16));
        a00 += p0 * v0; a01 += p0 * v1;
        a10 += p1 * v0; a11 += p1 * v1;
    }
    for (int jj = w; jj < deg1; jj += 4) {
        int s;
        float p0, p1;
        if (jj < CAP) {
            s = ss[1][jj];
            p0 = se[1][2 * jj];
            p1 = se[1][2 * jj + 1];
        } else {
            s = srcc1[beg1 + jj];
            float2 ev = ((const float2*)el1)[s];
            p0 = __expf(lrelu(ev.x + er10) - fin_m[2]) * fin_inv[2];
            p1 = __expf(lrelu(ev.y + er11) - fin_m[3]) * fin_inv[3];
        }
        unsigned pk = xp[s * 64 + lane];
        float v0 = bf2f((bf16_t)(pk & 0xffffu));
        float v1 = bf2f((bf16_t)(pk >> 16));
        b00 += p0 * v0; b01 += p0 * v1;
        b10 += p1 * v0; b11 += p1 * v1;
    }
    sh[w][0 + 2 * lane] = a00;       sh[w][0 + 2 * lane + 1] = a01;
    sh[w][128 + 2 * lane] = a10;     sh[w][128 + 2 * lane + 1] = a11;
    sh[w][256 + 2 * lane] = b00;     sh[w][256 + 2 * lane + 1] = b01;
    sh[w][384 + 2 * lane] = b10;     sh[w][384 + 2 * lane + 1] = b11;
    __syncthreads();
#pragma unroll
    for (int rep = 0; rep < 2; ++rep) {
        int o = t + rep * 256;
        float v = sh[0][o] + sh[1][o] + sh[2][o] + sh[3][o];
        y1[(size_t)d * 512 + o] = f2bf(v);
    }
}

// ---------------- agg2: softmax + gather h1 rows -> y2[N,1024] --------------
__global__ void agg2_kernel(
    const int* __restrict__ offs0, const int* __restrict__ srcc0,
    const float* __restrict__ el0, const float* __restrict__ er0,
    const int* __restrict__ offs1, const int* __restrict__ srcc1,
    const float* __restrict__ el1, const float* __restrict__ er1,
    const bf16_t* __restrict__ h1, bf16_t* __restrict__ y2) {
    constexpr int CAP = 192;
    __shared__ float sh[4][1024];
    __shared__ int   ss[2][CAP];
    __shared__ float se[2][2 * CAP];
    __shared__ float fin_m[4], fin_inv[4];
    int d = blockIdx.x;
    int t = threadIdx.x;
    int w = t >> 6, lane = t & 63;
    int beg0 = offs0[d], deg0 = offs0[d + 1] - beg0;
    int beg1 = offs1[d], deg1 = offs1[d + 1] - beg1;
    int c0 = min(deg0, CAP), c1 = min(deg1, CAP);
    float er00 = er0[d * 2], er01 = er0[d * 2 + 1];
    float er10 = er1[d * 2], er11 = er1[d * 2 + 1];

    for (int j = t; j < c0; j += 256) {
        int s = srcc0[beg0 + j];
        ss[0][j] = s;
        float2 ev = ((const float2*)el0)[s];
        se[0][2 * j] = lrelu(ev.x + er00);
        se[0][2 * j + 1] = lrelu(ev.y + er01);
    }
    for (int j = t; j < c1; j += 256) {
        int s = srcc1[beg1 + j];
        ss[1][j] = s;
        float2 ev = ((const float2*)el1)[s];
        se[1][2 * j] = lrelu(ev.x + er10);
        se[1][2 * j + 1] = lrelu(ev.y + er11);
    }
    __syncthreads();
    if (w < 2) {
        int rel = w;
        int head = lane & 1;
        int cc = rel ? c1 : c0;
        int deg = rel ? deg1 : deg0;
        int beg = rel ? beg1 : beg0;
        const int* sc = rel ? srcc1 : srcc0;
        const float* elp = rel ? el1 : el0;
        float erh = rel ? (head ? er11 : er10) : (head ? er01 : er00);
        float m = -1e30f, s = 0.f;
        for (int j = lane >> 1; j < cc; j += 32) {
            float e = se[rel][2 * j + head];
            float mn = fmaxf(m, e);
            s = s * __expf(m - mn) + __expf(e - mn);
            m = mn;
        }
        for (int j = cc + (lane >> 1); j < deg; j += 32) {
            int sv = sc[beg + j];
            float e = lrelu(elp[sv * 2 + head] + erh);
            float mn = fmaxf(m, e);
            s = s * __expf(m - mn) + __expf(e - mn);
            m = mn;
        }
#pragma unroll
        for (int off = 2; off < 64; off <<= 1) {
            float om = __shfl_xor(m, off);
            float os = __shfl_xor(s, off);
            float mn = fmaxf(m, om);
            s = s * __expf(m - mn) + os * __expf(om - mn);
            m = mn;
        }
        if (lane < 2) {
            fin_m[rel * 2 + head] = m;
            fin_inv[rel * 2 + head] = 1.f / fmaxf(s, 1e-9f);
        }
    }
    __syncthreads();
    for (int i = t; i < 2 * c0; i += 256)
        se[0][i] = __expf(se[0][i] - fin_m[i & 1]) * fin_inv[i & 1];
    for (int i = t; i < 2 * c1; i += 256)
        se[1][i] = __expf(se[1][i] - fin_m[2 + (i & 1)]) * fin_inv[2 + (i & 1)];
    __syncthreads();

    const uint2* hp = (const uint2*)h1;     // row = 64 uint2 (256 dims)
    float a0[4] = {}, a1[4] = {};           // rel0: head0/head1, 4 dims
    float b0v[4] = {}, b1v[4] = {};         // rel1
    for (int jj = w; jj < deg0; jj += 4) {
        int s;
        float p0, p1;
        if (jj < CAP) {
            s = ss[0][jj];
            p0 = se[0][2 * jj];
            p1 = se[0][2 * jj + 1];
        } else {
            s = srcc0[beg0 + jj];
            float2 ev = ((const float2*)el0)[s];
            p0 = __expf(lrelu(ev.x + er00) - fin_m[0]) * fin_inv[0];
            p1 = __expf(lrelu(ev.y + er01) - fin_m[1]) * fin_inv[1];
        }
        uint2 pk = hp[s * 64 + lane];
        float v0 = bf2f((bf16_t)(pk.x & 0xffffu));
        float v1 = bf2f((bf16_t)(pk.x >> 16));
        float v2 = bf2f((bf16_t)(pk.y & 0xffffu));
        float v3 = bf2f((bf16_t)(pk.y >> 16));
        a0[0] += p0 * v0; a0[1] += p0 * v1; a0[2] += p0 * v2; a0[3] += p0 * v3;
        a1[0] += p1 * v0; a1[1] += p1 * v1; a1[2] += p1 * v2; a1[3] += p1 * v3;
    }
    for (int jj = w; jj < deg1; jj += 4) {
        int s;
        float p0, p1;
        if (jj < CAP) {
            s = ss[1][jj];
            p0 = se[1][2 * jj];
            p1 = se[1][2 * jj + 1];
        } else {
            s = srcc1[beg1 + jj];
            float2 ev = ((const float2*)el1)[s];
            p0 = __expf(lrelu(ev.x + er10) - fin_m[2]) * fin_inv[2];
            p1 = __expf(lrelu(ev.y + er11) - fin_m[3]) * fin_inv[3];
        }
        uint2 pk = hp[s * 64 + lane];
        float v0 = bf2f((bf16_t)(pk.x & 0xffffu));
        float v1 = bf2f((bf16_t)(pk.x >> 16));
        float v2 = bf2f((bf16_t)(pk.y & 0xffffu));
        float v3 = bf2f((bf16_t)(pk.y >> 16));
        b0v[0] += p0 * v0; b0v[1] += p0 * v1; b0v[2] += p0 * v2; b0v[3] += p0 * v3;
        b1v[0] += p1 * v0; b1v[1] += p1 * v1; b1v[2] += p1 * v2; b1v[3] += p1 * v3;
    }
#pragma unroll
    for (int k = 0; k < 4; ++k) {
        sh[w][0 + 4 * lane + k] = a0[k];
        sh[w][256 + 4 * lane + k] = a1[k];
        sh[w][512 + 4 * lane + k] = b0v[k];
        sh[w][768 + 4 * lane + k] = b1v[k];
    }
    __syncthreads();
#pragma unroll
    for (int rep = 0; rep < 4; ++rep) {
        int o = t + rep * 256;
        float v = sh[0][o] + sh[1][o] + sh[2][o] + sh[3][o];
        y2[(size_t)d * 1024 + o] = f2bf(v);
    }
}

// -------- gemm1: h1 = relu(y1 @ Wc1 + bc1); epilogue: el2/er2 atomics --------
// K=512, M=256; block 256 = 4 waves, wave = 16 rows x 64 cols; grid (4, 313).
__global__ void gemm1_kernel(const bf16_t* __restrict__ A, const bf16_t* __restrict__ Wf,
                             const float* __restrict__ bc1, bf16_t* __restrict__ h1,
                             const float* __restrict__ wal2, const float* __restrict__ war2,
                             float* __restrict__ el2_0, float* __restrict__ er2_0,
                             float* __restrict__ el2_1, float* __restrict__ er2_1,
                             int n) {
    constexpr int K = 512, M = 256, KS = 16;
    int w = threadIdx.x >> 6, lane = threadIdx.x & 63;
    int q = lane >> 4, m16 = lane & 15;
    int rf = blockIdx.y * 64 + w * 16;
    if (rf >= n) return;
    f32x4 acc[4] = {};
    const bf16_t* Arow = A + (size_t)(rf + m16) * K + q * 8;
    for (int ks = 0; ks < KS; ++ks) {
        short8 af = *(const short8*)(Arow + ks * 32);
#pragma unroll
        for (int f = 0; f < 4; ++f) {
            int ct = blockIdx.x * 4 + f;
            short8 bfr = *(const short8*)(Wf + ((size_t)(ct * KS + ks) * 64 + lane) * 8);
            acc[f] = __builtin_amdgcn_mfma_f32_16x16x32_bf16(af, bfr, acc[f], 0, 0, 0);
        }
    }
    int col0 = blockIdx.x * 64;
    float del[2][2][4] = {};   // [rel][h][r]
    float der[2][2][4] = {};
#pragma unroll
    for (int f = 0; f < 4; ++f) {
        int col = col0 + f * 16 + m16;
        float bcv = bc1[col];
        float wle[2][2], wre[2][2];
#pragma unroll
        for (int rel = 0; rel < 2; ++rel)
#pragma unroll
            for (int h = 0; h < 2; ++h) {
                wle[rel][h] = wal2[(rel * 2 + h) * 256 + col];
                wre[rel][h] = war2[(rel * 2 + h) * 256 + col];
            }
#pragma unroll
        for (int r = 0; r < 4; ++r) {
            int row = rf + q * 4 + r;
            float v = fmaxf(acc[f][r] + bcv, 0.f);
            bf16_t hb = f2bf(v);
            h1[(size_t)row * M + col] = hb;
            float vb = bf2f(hb);
#pragma unroll
            for (int rel = 0; rel < 2; ++rel)
#pragma unroll
                for (int h = 0; h < 2; ++h) {
                    del[rel][h][r] += vb * wle[rel][h];
                    der[rel][h][r] += vb * wre[rel][h];
                }
        }
    }
#pragma unroll
    for (int off = 1; off < 16; off <<= 1) {
#pragma unroll
        for (int rel = 0; rel < 2; ++rel)
#pragma unroll
            for (int h = 0; h < 2; ++h)
#pragma unroll
                for (int r = 0; r < 4; ++r) {
                    del[rel][h][r] += __shfl_xor(del[rel][h][r], off);
                    der[rel][h][r] += __shfl_xor(der[rel][h][r], off);
                }
    }
    if (m16 == 0) {
#pragma unroll
        for (int r = 0; r < 4; ++r) {
            int row = rf + q * 4 + r;
            atomicAdd(&el2_0[row * 2 + 0], del[0][0][r]);
            atomicAdd(&el2_0[row * 2 + 1], del[0][1][r]);
            atomicAdd(&el2_1[row * 2 + 0], del[1][0][r]);
            atomicAdd(&el2_1[row * 2 + 1], del[1][1][r]);
            atomicAdd(&er2_0[row * 2 + 0], der[0][0][r]);
            atomicAdd(&er2_0[row * 2 + 1], der[0][1][r]);
            atomicAdd(&er2_1[row * 2 + 0], der[1][0][r]);
            atomicAdd(&er2_1[row * 2 + 1], der[1][1][r]);
        }
    }
}

// -------- gemm2: out = y2 @ Wc2 + bc2 (final store, flag dtype) --------
// K=1024, M=128; grid (2, 313).
__global__ void gemm2_kernel(const bf16_t* __restrict__ A, const bf16_t* __restrict__ Wf,
                             const float* __restrict__ bc2, void* __restrict__ out,
                             const int* __restrict__ flag, int n) {
    constexpr int K = 1024, M = 128, KS = 32;
    int w = threadIdx.x >> 6, lane = threadIdx.x & 63;
    int q = lane >> 4, m16 = lane & 15;
    int rf = blockIdx.y * 64 + w * 16;
    if (rf >= n) return;
    f32x4 acc[4] = {};
    const bf16_t* Arow = A + (size_t)(rf + m16) * K + q * 8;
    for (int ks = 0; ks < KS; ++ks) {
        short8 af = *(const short8*)(Arow + ks * 32);
#pragma unroll
        for (int f = 0; f < 4; ++f) {
            int ct = blockIdx.x * 4 + f;
            short8 bfr = *(const short8*)(Wf + ((size_t)(ct * KS + ks) * 64 + lane) * 8);
            acc[f] = __builtin_amdgcn_mfma_f32_16x16x32_bf16(af, bfr, acc[f], 0, 0, 0);
        }
    }
    int col0 = blockIdx.x * 64;
    int fl = *flag;
#pragma unroll
    for (int f = 0; f < 4; ++f) {
        int col = col0 + f * 16 + m16;
        float bcv = bc2[col];
#pragma unroll
        for (int r = 0; r < 4; ++r) {
            int row = rf + q * 4 + r;
            float v = acc[f][r] + bcv;
            if (fl) ((float*)out)[(size_t)row * M + col] = v;
            else    ((bf16_t*)out)[(size_t)row * M + col] = f2bf(v);
        }
    }
}

extern "C" void kernel_launch(void* const* d_in, const int* in_sizes, int n_in,
                              void* d_out, int out_size, void* d_ws, size_t ws_size,
                              hipStream_t stream) {
    (void)in_sizes; (void)n_in; (void)out_size; (void)ws_size;
    const int* src0 = (const int*)d_in[1];
    const int* dst0 = (const int*)d_in[2];
    const int* src1 = (const int*)d_in[3];
    const int* dst1 = (const int*)d_in[4];

    char* ws = (char*)d_ws;
    size_t off = 0;
    auto alloc = [&](size_t bytes) -> void* {
        void* p = ws + off;
        off = (off + bytes + 255) & ~(size_t)255;
        return p;
    };
    int* flag = (int*)alloc(4);
    static const int tn[NT] = {NN * 128,
                               128 * 512, 512, 512, 512,
                               128 * 512, 512, 512, 512,
                               256 * 256, 256, 256, 256,
                               256 * 256, 256, 256, 256};
    bf16_t* tb[NT];
    for (int i = 0; i < NT; ++i) tb[i] = (bf16_t*)alloc((size_t)tn[i] * 2);
    bf16_t* xb = tb[0];

    bf16_t* Wc1f = (bf16_t*)alloc((size_t)512 * 256 * 2);
    bf16_t* Wc2f = (bf16_t*)alloc((size_t)1024 * 128 * 2);
    float* wal1 = (float*)alloc(512 * 4);
    float* war1 = (float*)alloc(512 * 4);
    float* wal2 = (float*)alloc(1024 * 4);
    float* war2 = (float*)alloc(1024 * 4);
    float* bc1  = (float*)alloc(256 * 4);
    float* bc2  = (float*)alloc(128 * 4);

    // zero region: cnt0, cnt1, el2/er2 x2 rel (atomic targets)
    char* zbeg = ws + off;
    int* cnt0 = (int*)alloc(NN * 4);
    int* cnt1 = (int*)alloc(NN * 4);
    float* el2_0 = (float*)alloc(NN * 2 * 4);
    float* er2_0 = (float*)alloc(NN * 2 * 4);
    float* el2_1 = (float*)alloc(NN * 2 * 4);
    float* er2_1 = (float*)alloc(NN * 2 * 4);
    char* zend = ws + off;
    int zcount = (int)((zend - zbeg) >> 2);

    int* offs0 = (int*)alloc((NN + 1) * 4);
    int* offs1 = (int*)alloc((NN + 1) * 4);
    int* cur0  = (int*)alloc(NN * 4);
    int* cur1  = (int*)alloc(NN * 4);
    int* srcc0 = (int*)alloc(NE * 4);
    int* srcc1 = (int*)alloc(NE * 4);
    float* el1_0 = (float*)alloc(NN * 2 * 4);
    float* er1_0 = (float*)alloc(NN * 2 * 4);
    float* el1_1 = (float*)alloc(NN * 2 * 4);
    float* er1_1 = (float*)alloc(NN * 2 * 4);
    bf16_t* h1 = (bf16_t*)alloc((size_t)NN * 256 * 2);
    bf16_t* Y  = (bf16_t*)alloc((size_t)NN * 1024 * 2);   // y1 [N,512] then y2 [N,1024]
    bf16_t* y1 = Y;
    bf16_t* y2 = Y;

    // ---- detect ----
    detect_kernel<<<1, 64, 0, stream>>>((const unsigned*)d_in[0], flag);

    // ---- convert + zero (flat grid) ----
    CzArgs cz;
    static const int din_idx[NT] = {0, 5, 6, 7, 8, 9, 10, 11, 12,
                                    13, 14, 15, 16, 17, 18, 19, 20};
    int total_blocks = 0;
    for (int i = 0; i < NT; ++i) {
        cz.src[i] = d_in[din_idx[i]];
        cz.dst[i] = tb[i];
        cz.n[i] = tn[i];
        cz.nblk[i] = (tn[i] + 255) / 256;
        total_blocks += cz.nblk[i];
    }
    cz.zero_ptr = (int*)zbeg;
    cz.zn = zcount;
    cz.nblk[NT] = (zcount + 255) / 256;
    total_blocks += cz.nblk[NT];
    convzero_kernel<<<total_blocks, 256, 0, stream>>>(cz, flag);

    // ---- prep: wal/war, biases, combined-weight frag repack ----
    PrepArgs pp;
    pp.W1[0] = tb[1];  pp.W1[1] = tb[5];
    pp.W2[0] = tb[9];  pp.W2[1] = tb[13];
    pp.al1[0] = tb[2]; pp.ar1[0] = tb[3];
    pp.al1[1] = tb[6]; pp.ar1[1] = tb[7];
    pp.al2[0] = tb[10]; pp.ar2[0] = tb[11];
    pp.al2[1] = tb[14]; pp.ar2[1] = tb[15];
    pp.b1[0] = tb[4];  pp.b1[1] = tb[8];
    pp.b2[0] = tb[12]; pp.b2[1] = tb[16];
    pp.wal1 = wal1; pp.war1 = war1;
    pp.wal2 = wal2; pp.war2 = war2;
    pp.bc1 = bc1; pp.bc2 = bc2;
    pp.Wc1f = Wc1f; pp.Wc2f = Wc2f;
    prep_kernel<<<142, 256, 0, stream>>>(pp);

    // ---- CSR build ----
    Csr2 cs;
    cs.src[0] = src0; cs.src[1] = src1;
    cs.dst[0] = dst0; cs.dst[1] = dst1;
    cs.cnt[0] = cnt0; cs.cnt[1] = cnt1;
    cs.offs[0] = offs0; cs.offs[1] = offs1;
    cs.cursor[0] = cur0; cs.cursor[1] = cur1;
    cs.srcc[0] = srcc0; cs.srcc[1] = srcc1;
    const int EB = (NE + 255) / 256;
    hist2_kernel<<<dim3(EB, 2), 256, 0, stream>>>(cs, NE);
    scan2_kernel<<<2, 256, 0, stream>>>(cs, NN);
    scatter2_kernel<<<dim3(EB, 2), 256, 0, stream>>>(cs, NE);

    // ---- Layer 1 ----
    elr1_kernel<<<NN / 4, 256, 0, stream>>>(xb, wal1, war1, el1_0, er1_0, el1_1, er1_1);
    agg1_kernel<<<NN, 256, 0, stream>>>(offs0, srcc0, el1_0, er1_0,
                                        offs1, srcc1, el1_1, er1_1, xb, y1);
    gemm1_kernel<<<dim3(4, 313), 256, 0, stream>>>(
        y1, Wc1f, bc1, h1, wal2, war2, el2_0, er2_0, el2_1, er2_1, NN);

    // ---- Layer 2 ----
    agg2_kernel<<<NN, 256, 0, stream>>>(offs0, srcc0, el2_0, er2_0,
                                        offs1, srcc1, el2_1, er2_1, h1, y2);
    gemm2_kernel<<<dim3(2, 313), 256, 0, stream>>>(y2, Wc2f, bc2, d_out, flag, NN);
}